// Round 1
// baseline (620.941 us; speedup 1.0000x reference)
//
#include <hip/hip_runtime.h>
#include <cmath>

constexpr int LVLS = 16;
constexpr unsigned TBLN = 1u << 19;          // T
constexpr unsigned P1 = 2654435761u;         // multiplies z
constexpr unsigned P2 = 805459861u;          // multiplies y

struct GridParams { unsigned res[LVLS]; unsigned dense_mask; };

__global__ __launch_bounds__(256)
void nerf_fused(const float* __restrict__ input,   // [N,6]
                const float* __restrict__ table,   // [L,T,2]
                const float* __restrict__ w1,      // [32,128]
                const float* __restrict__ w2,      // [128,31]
                const float* __restrict__ c1,      // [46,64]
                const float* __restrict__ c2,      // [64,64]
                const float* __restrict__ c3,      // [64,3]
                float* __restrict__ out,           // [N,4]
                GridParams gp, int N)
{
    __shared__ float sin_[256 * 6];
    const int tid = threadIdx.x;
    const int n0  = blockIdx.x * 256;

    // coalesced input staging
    #pragma unroll
    for (int t = 0; t < 6; ++t) {
        int i = t * 256 + tid;
        int gi = n0 * 6 + i;
        sin_[i] = (gi < N * 6) ? input[gi] : 0.f;
    }
    __syncthreads();

    const int n = n0 + tid;
    if (n >= N) return;

    const float i0 = sin_[tid*6+0], i1 = sin_[tid*6+1], i2 = sin_[tid*6+2];
    const float i3 = sin_[tid*6+3], i4 = sin_[tid*6+4], i5 = sin_[tid*6+5];

    // ---- position -> [0,1]
    const float px = fminf(fmaxf((i0 + 16.f) * (1.f/32.f), 0.f), 1.f);
    const float py = fminf(fmaxf((i1 + 16.f) * (1.f/32.f), 0.f), 1.f);
    const float pz = fminf(fmaxf((i2 + 16.f) * (1.f/32.f), 0.f), 1.f);

    // ---- multires hash-grid encode -> g[32]
    float g[32];
    #pragma unroll 4
    for (int l = 0; l < LVLS; ++l) {
        const unsigned res   = gp.res[l];
        const bool     dense = (gp.dense_mask >> l) & 1u;
        const unsigned rm1   = res - 1u;
        const float    rf    = (float)res - 1.0f;

        const float posx = px * rf, posy = py * rf, posz = pz * rf;
        const float fx = floorf(posx), fy = floorf(posy), fz = floorf(posz);
        const float wx = posx - fx,  wy = posy - fy,  wz = posz - fz;
        const unsigned x0 = (unsigned)fx, y0 = (unsigned)fy, z0 = (unsigned)fz;

        const float* tb = table + (size_t)l * (size_t)TBLN * 2u;

        float a0 = 0.f, a1 = 0.f;
        #pragma unroll
        for (int corner = 0; corner < 8; ++corner) {
            const unsigned ox = (corner >> 2) & 1u;   // i -> x (outer in OFFSETS)
            const unsigned oy = (corner >> 1) & 1u;   // j -> y
            const unsigned oz = corner & 1u;          // k -> z
            const unsigned cx = min(x0 + ox, rm1);
            const unsigned cy = min(y0 + oy, rm1);
            const unsigned cz = min(z0 + oz, rm1);
            unsigned idx;
            if (dense) idx = (cx + cy * res + cz * res * res) & (TBLN - 1u);
            else       idx = (cx ^ (cy * P2) ^ (cz * P1)) & (TBLN - 1u);
            const float2 f = *reinterpret_cast<const float2*>(tb + (size_t)idx * 2u);
            const float wcx = ox ? wx : 1.f - wx;
            const float wcy = oy ? wy : 1.f - wy;
            const float wcz = oz ? wz : 1.f - wz;
            const float wc = wcx * wcy * wcz;
            a0 += wc * f.x;
            a1 += wc * f.y;
        }
        g[2*l]   = a0;
        g[2*l+1] = a1;
    }

    // ---- sigma MLP: h31 = relu(g @ w1) @ w2   (w1:[32,128], w2:[128,31])
    float h31[31];
    #pragma unroll
    for (int j = 0; j < 31; ++j) h31[j] = 0.f;

    for (int ho = 0; ho < 128; ho += 8) {
        float t[8];
        #pragma unroll
        for (int c = 0; c < 8; ++c) t[c] = 0.f;
        #pragma unroll
        for (int k = 0; k < 32; ++k) {
            const float gk = g[k];
            #pragma unroll
            for (int c = 0; c < 8; ++c) t[c] += gk * w1[k * 128 + ho + c];
        }
        #pragma unroll
        for (int c = 0; c < 8; ++c) t[c] = fmaxf(t[c], 0.f);
        #pragma unroll
        for (int c = 0; c < 8; ++c) {
            const float tc = t[c];
            #pragma unroll
            for (int j = 0; j < 31; ++j) h31[j] += tc * w2[(ho + c) * 31 + j];
        }
    }

    // ---- SH degree 4 encode (replicate the (d+1)/2 then *2-1 rounding)
    float in46[46];
    {
        const float x = ((i3 + 1.f) * 0.5f) * 2.f - 1.f;
        const float y = ((i4 + 1.f) * 0.5f) * 2.f - 1.f;
        const float z = ((i5 + 1.f) * 0.5f) * 2.f - 1.f;
        const float x2 = x*x, y2 = y*y, z2 = z*z;
        const float xy = x*y, yz = y*z, xz = x*z;
        in46[0]  = 0.28209479177387814f;
        in46[1]  = -0.48860251190291987f * y;
        in46[2]  =  0.48860251190291987f * z;
        in46[3]  = -0.48860251190291987f * x;
        in46[4]  =  1.0925484305920792f * xy;
        in46[5]  = -1.0925484305920792f * yz;
        in46[6]  =  0.94617469575756f * z2 - 0.31539156525252005f;
        in46[7]  = -1.0925484305920792f * xz;
        in46[8]  =  0.5462742152960396f * (x2 - y2);
        in46[9]  =  0.5900435899266435f * y * (-3.0f * x2 + y2);
        in46[10] =  2.890611442640554f * xy * z;
        in46[11] =  0.4570457994644657f * y * (1.0f - 5.0f * z2);
        in46[12] =  0.3731763325901154f * z * (5.0f * z2 - 3.0f);
        in46[13] =  0.4570457994644657f * x * (1.0f - 5.0f * z2);
        in46[14] =  1.445305721320277f * z * (x2 - y2);
        in46[15] =  0.5900435899266435f * x * (-x2 + 3.0f * y2);
    }
    #pragma unroll
    for (int m = 0; m < 30; ++m) in46[16 + m] = h31[1 + m];

    // ---- color MLP layer 1: hc[64] = relu(in46 @ c1)
    float hc[64];
    for (int o = 0; o < 64; o += 8) {
        float t[8];
        #pragma unroll
        for (int c = 0; c < 8; ++c) t[c] = 0.f;
        #pragma unroll
        for (int k = 0; k < 46; ++k) {
            const float vk = in46[k];
            #pragma unroll
            for (int c = 0; c < 8; ++c) t[c] += vk * c1[k * 64 + o + c];
        }
        #pragma unroll
        for (int c = 0; c < 8; ++c) hc[o + c] = fmaxf(t[c], 0.f);
    }

    // ---- layer 2 + layer 3 fused: acc3 += relu(hc @ c2) @ c3
    float acc3[3] = {0.f, 0.f, 0.f};
    for (int o = 0; o < 64; o += 8) {
        float t[8];
        #pragma unroll
        for (int c = 0; c < 8; ++c) t[c] = 0.f;
        #pragma unroll
        for (int k = 0; k < 64; ++k) {
            const float vk = hc[k];
            #pragma unroll
            for (int c = 0; c < 8; ++c) t[c] += vk * c2[k * 64 + o + c];
        }
        #pragma unroll
        for (int c = 0; c < 8; ++c) {
            const float tc = fmaxf(t[c], 0.f);
            #pragma unroll
            for (int j = 0; j < 3; ++j) acc3[j] += tc * c3[(o + c) * 3 + j];
        }
    }

    // ---- sigmoid + store
    float4 o4;
    o4.x = 1.f / (1.f + __expf(-acc3[0]));
    o4.y = 1.f / (1.f + __expf(-acc3[1]));
    o4.z = 1.f / (1.f + __expf(-acc3[2]));
    o4.w = h31[0];   // sigma
    *reinterpret_cast<float4*>(out + (size_t)n * 4u) = o4;
}

extern "C" void kernel_launch(void* const* d_in, const int* in_sizes, int n_in,
                              void* d_out, int out_size, void* d_ws, size_t ws_size,
                              hipStream_t stream) {
    (void)n_in; (void)d_ws; (void)ws_size; (void)out_size;
    const float* input = (const float*)d_in[0];
    const float* table = (const float*)d_in[1];
    const float* w1    = (const float*)d_in[2];
    const float* w2    = (const float*)d_in[3];
    const float* c1    = (const float*)d_in[4];
    const float* c2    = (const float*)d_in[5];
    const float* c3    = (const float*)d_in[6];
    float* out = (float*)d_out;
    const int N = in_sizes[0] / 6;

    // replicate numpy's RES computation in float64
    GridParams gp;
    const double pls = std::exp2(std::log2(2048.0 * 16.0 / 16.0) / 15.0);
    unsigned dm = 0;
    for (int i = 0; i < LVLS; ++i) {
        const double r = std::ceil(16.0 * std::pow(pls, (double)i));
        const long long ri = (long long)r;
        gp.res[i] = (unsigned)ri;
        if (ri * ri * ri <= (long long)TBLN) dm |= (1u << i);
    }
    gp.dense_mask = dm;

    dim3 grid((N + 255) / 256), block(256);
    hipLaunchKernelGGL(nerf_fused, grid, block, 0, stream,
                       input, table, w1, w2, c1, c2, c3, out, gp, N);
}

// Round 4
// 323.520 us; speedup vs baseline: 1.9193x; 1.9193x over previous
//
#include <hip/hip_runtime.h>
#include <cmath>

constexpr int LVLS = 16;
constexpr unsigned TBLN = 1u << 19;
constexpr unsigned P1 = 2654435761u;   // multiplies z
constexpr unsigned P2 = 805459861u;    // multiplies y

typedef __attribute__((ext_vector_type(8))) short short8;
typedef __attribute__((ext_vector_type(4))) float f32x4;
typedef __attribute__((ext_vector_type(4))) unsigned uint4v;
typedef __attribute__((ext_vector_type(2))) unsigned uint2v;

struct GridParams { unsigned res[LVLS]; unsigned dense_mask; };

__device__ __host__ __forceinline__ unsigned f2bf(float f) {
    union { float f; unsigned u; } v; v.f = f;
    unsigned u = v.u;
    u += 0x7fffu + ((u >> 16) & 1u);   // RNE
    return u >> 16;
}
__device__ __host__ __forceinline__ float bf2f(unsigned h) {
    union { unsigned u; float f; } v; v.u = h << 16; return v.f;
}
__device__ __forceinline__ unsigned pkbf(float lo, float hi) {
    return f2bf(lo) | (f2bf(hi) << 16);
}

#define LGKM0() do { asm volatile("s_waitcnt lgkmcnt(0)" ::: "memory"); \
                     __builtin_amdgcn_sched_barrier(0); } while (0)

#define MFMA(a,b,c) __builtin_amdgcn_mfma_f32_16x16x32_bf16((a),(b),(c),0,0,0)

// ---------------------------------------------------------------------------
// Prep: pack MLP weights into bf16 MFMA A-fragments in d_ws.
// Fragment f, lane l -> uint4 (8 bf16 = A[o=base+(l&15)][k=(l>>4)*8+i]).
// f 0..7  : W1 (hi only)      o=f*16+c,  k=g*8+i (K=32)
// f 8..15 : W2 (hi only)      idx=f-8: o=(idx>>2)*16+c (o<31), k=(idx&3)*32+g*8+i
// f 16..23: C1 hi | 24..31: C1 lo   idx&7: o=(idx>>1)*16+c, k=(idx&1)*32+g*8+i
//          X2-col remap: k<16->c1[k], k==16->0, 17<=k<=46->c1[k-1], else 0
// f 32..39: C2 hi | 40..47: C2 lo   c2[k*64+o]
// f 48..49: C3 hi | 50..51: C3 lo   ks=idx&1: o=c<3 ? c3[k*3+c] : 0
// ---------------------------------------------------------------------------
__global__ void prep_frags(const float* __restrict__ w1, const float* __restrict__ w2,
                           const float* __restrict__ c1, const float* __restrict__ c2,
                           const float* __restrict__ c3, uint4v* __restrict__ wf) {
    const int f = blockIdx.x;
    const int l = threadIdx.x;
    const int g = l >> 4, c = l & 15;
    float v[8];
    bool lo_part = false;
    if (f < 8) {
        int o = f * 16 + c;
        #pragma unroll
        for (int i = 0; i < 8; ++i) { int k = g * 8 + i; v[i] = w1[k * 128 + o]; }
    } else if (f < 16) {
        int idx = f - 8; int o = (idx >> 2) * 16 + c; int ks = idx & 3;
        #pragma unroll
        for (int i = 0; i < 8; ++i) {
            int k = ks * 32 + g * 8 + i;
            v[i] = (o < 31) ? w2[k * 31 + o] : 0.f;
        }
    } else if (f < 32) {
        int idx = (f - 16) & 7; lo_part = (f >= 24);
        int o = (idx >> 1) * 16 + c; int ks = idx & 1;
        #pragma unroll
        for (int i = 0; i < 8; ++i) {
            int k = ks * 32 + g * 8 + i;
            float x = 0.f;
            if (k < 16) x = c1[k * 64 + o];
            else if (k >= 17 && k <= 46) x = c1[(k - 1) * 64 + o];
            v[i] = x;
        }
    } else if (f < 48) {
        int idx = (f - 32) & 7; lo_part = (f >= 40);
        int o = (idx >> 1) * 16 + c; int ks = idx & 1;
        #pragma unroll
        for (int i = 0; i < 8; ++i) { int k = ks * 32 + g * 8 + i; v[i] = c2[k * 64 + o]; }
    } else {
        int idx = f - 48; lo_part = (idx >= 2); int ks = idx & 1;
        #pragma unroll
        for (int i = 0; i < 8; ++i) {
            int k = ks * 32 + g * 8 + i;
            v[i] = (c < 3) ? c3[k * 3 + c] : 0.f;
        }
    }
    if (lo_part) {
        #pragma unroll
        for (int i = 0; i < 8; ++i) v[i] = v[i] - bf2f(f2bf(v[i]));
    }
    uint4v q = { pkbf(v[0], v[1]), pkbf(v[2], v[3]), pkbf(v[4], v[5]), pkbf(v[6], v[7]) };
    wf[f * 64 + l] = q;
}

// ---------------------------------------------------------------------------
// Main fused kernel. 256 threads = 4 waves, each wave owns 64 points and is
// fully independent (no __syncthreads). Per-wave LDS 9216 B, reused in phases:
//   phase 1 (grid + sigma MLP): rows [64] stride 80 B  ([0,5120))
//   phase 2 (color, per 32-pt chunk): hi plane [32]x144B at 0, lo plane at 4608
// Color MLP in double-bf16: out = Whi*Bhi + Whi*Blo + Wlo*Bhi.
// ---------------------------------------------------------------------------
__global__ __launch_bounds__(256)
void nerf_main(const float* __restrict__ input, const float* __restrict__ table,
               const uint4v* __restrict__ wf, float* __restrict__ out,
               GridParams gp, int N)
{
    __shared__ unsigned char smem[4 * 9216];
    const int tid  = threadIdx.x;
    const int lane = tid & 63;
    const int w    = tid >> 6;
    const int g    = lane >> 4, c = lane & 15;
    unsigned char* const sc = smem + w * 9216;

    const int n = blockIdx.x * 256 + tid;

    const float2* ip = reinterpret_cast<const float2*>(input + (size_t)n * 6);
    const float2 iA = ip[0], iB = ip[1], iC = ip[2];

    const float px = fminf(fmaxf((iA.x + 16.f) * (1.f / 32.f), 0.f), 1.f);
    const float py = fminf(fmaxf((iA.y + 16.f) * (1.f / 32.f), 0.f), 1.f);
    const float pz = fminf(fmaxf((iB.x + 16.f) * (1.f / 32.f), 0.f), 1.f);

    // ---- multires hash-grid encode -> Xg LDS rows (bf16, stride 80B)
    for (int lo = 0; lo < 4; ++lo) {
        unsigned pk4[4];
        #pragma unroll
        for (int li = 0; li < 4; ++li) {
            const int l = lo * 4 + li;
            const unsigned res = gp.res[l];
            const bool dense = (gp.dense_mask >> l) & 1u;
            const unsigned rm1 = res - 1u;
            const float rf = (float)res - 1.f;
            const float posx = px * rf, posy = py * rf, posz = pz * rf;
            const float fx = floorf(posx), fy = floorf(posy), fz = floorf(posz);
            const float wx = posx - fx, wy = posy - fy, wz = posz - fz;
            const unsigned x0 = (unsigned)fx, y0 = (unsigned)fy, z0 = (unsigned)fz;
            const unsigned x1 = min(x0 + 1u, rm1), y1 = min(y0 + 1u, rm1), z1 = min(z0 + 1u, rm1);
            const float* tb = table + (size_t)l * (size_t)TBLN * 2u;
            const float sx[2] = {1.f - wx, wx}, sy[2] = {1.f - wy, wy}, sz[2] = {1.f - wz, wz};
            unsigned tx[2], ty[2], tz[2];
            if (dense) { tx[0]=x0; tx[1]=x1; ty[0]=y0*res; ty[1]=y1*res; tz[0]=z0*res*res; tz[1]=z1*res*res; }
            else       { tx[0]=x0; tx[1]=x1; ty[0]=y0*P2;  ty[1]=y1*P2;  tz[0]=z0*P1;      tz[1]=z1*P1; }
            float a0 = 0.f, a1 = 0.f;
            if (dense) {
                #pragma unroll
                for (int corner = 0; corner < 8; ++corner) {
                    const int ox = (corner >> 2) & 1, oy = (corner >> 1) & 1, oz = corner & 1;
                    const unsigned idx = (tx[ox] + ty[oy] + tz[oz]) & (TBLN - 1u);
                    const float2 f2 = *reinterpret_cast<const float2*>(tb + (size_t)idx * 2u);
                    const float wc = sx[ox] * sy[oy] * sz[oz];
                    a0 += wc * f2.x; a1 += wc * f2.y;
                }
            } else {
                #pragma unroll
                for (int corner = 0; corner < 8; ++corner) {
                    const int ox = (corner >> 2) & 1, oy = (corner >> 1) & 1, oz = corner & 1;
                    const unsigned idx = (tx[ox] ^ ty[oy] ^ tz[oz]) & (TBLN - 1u);
                    const float2 f2 = *reinterpret_cast<const float2*>(tb + (size_t)idx * 2u);
                    const float wc = sx[ox] * sy[oy] * sz[oz];
                    a0 += wc * f2.x; a1 += wc * f2.y;
                }
            }
            pk4[li] = pkbf(a0, a1);
        }
        uint4v q = { pk4[0], pk4[1], pk4[2], pk4[3] };
        *reinterpret_cast<uint4v*>(sc + lane * 80 + lo * 16) = q;
    }

    // ---- SH degree 4, hi/lo packed in regs
    unsigned shq[8], shl[8];
    {
        const float x = iB.y, y = iC.x, z = iC.y;
        const float x2 = x*x, y2 = y*y, z2 = z*z;
        const float xy = x*y, yz = y*z, xz = x*z;
        float s[16];
        s[0]  = 0.28209479177387814f;
        s[1]  = -0.48860251190291987f * y;
        s[2]  =  0.48860251190291987f * z;
        s[3]  = -0.48860251190291987f * x;
        s[4]  =  1.0925484305920792f * xy;
        s[5]  = -1.0925484305920792f * yz;
        s[6]  =  0.94617469575756f * z2 - 0.31539156525252005f;
        s[7]  = -1.0925484305920792f * xz;
        s[8]  =  0.5462742152960396f * (x2 - y2);
        s[9]  =  0.5900435899266435f * y * (-3.0f * x2 + y2);
        s[10] =  2.890611442640554f * xy * z;
        s[11] =  0.4570457994644657f * y * (1.0f - 5.0f * z2);
        s[12] =  0.3731763325901154f * z * (5.0f * z2 - 3.0f);
        s[13] =  0.4570457994644657f * x * (1.0f - 5.0f * z2);
        s[14] =  1.445305721320277f * z * (x2 - y2);
        s[15] =  0.5900435899266435f * x * (-x2 + 3.0f * y2);
        #pragma unroll
        for (int i = 0; i < 8; ++i) {
            unsigned h0 = f2bf(s[2*i]), h1 = f2bf(s[2*i+1]);
            shq[i] = h0 | (h1 << 16);
            shl[i] = pkbf(s[2*i] - bf2f(h0), s[2*i+1] - bf2f(h1));
        }
    }

    LGKM0();

    const f32x4 zz = {0.f, 0.f, 0.f, 0.f};

    // hoist Xg B-fragments
    short8 xb[4];
    #pragma unroll
    for (int pt = 0; pt < 4; ++pt)
        xb[pt] = *reinterpret_cast<const short8*>(sc + (pt * 16 + c) * 80 + g * 16);

    // ---- sigma MLP: L1 (32->128, relu) + L2 (128->32), plain bf16
    f32x4 acc2[2][4];
    #pragma unroll
    for (int t = 0; t < 2; ++t)
        #pragma unroll
        for (int pt = 0; pt < 4; ++pt) acc2[t][pt] = zz;

    #pragma unroll
    for (int oc = 0; oc < 4; ++oc) {
        short8 a1_0 = __builtin_bit_cast(short8, wf[(2 * oc + 0) * 64 + lane]);
        short8 a1_1 = __builtin_bit_cast(short8, wf[(2 * oc + 1) * 64 + lane]);
        f32x4 d1[2][4];
        #pragma unroll
        for (int pt = 0; pt < 4; ++pt) {
            d1[0][pt] = MFMA(a1_0, xb[pt], zz);
            d1[1][pt] = MFMA(a1_1, xb[pt], zz);
        }
        #pragma unroll
        for (int t = 0; t < 2; ++t)
            #pragma unroll
            for (int pt = 0; pt < 4; ++pt) {
                const float e0 = fmaxf(d1[t][pt][0], 0.f), e1 = fmaxf(d1[t][pt][1], 0.f);
                const float e2 = fmaxf(d1[t][pt][2], 0.f), e3 = fmaxf(d1[t][pt][3], 0.f);
                uint2v q = { pkbf(e0, e1), pkbf(e2, e3) };
                *reinterpret_cast<uint2v*>(sc + (pt * 16 + c) * 80 + 32 * t + 8 * g) = q;
            }
        LGKM0();
        short8 a2_0 = __builtin_bit_cast(short8, wf[(8 + 0 * 4 + oc) * 64 + lane]);
        short8 a2_1 = __builtin_bit_cast(short8, wf[(8 + 1 * 4 + oc) * 64 + lane]);
        #pragma unroll
        for (int pt = 0; pt < 4; ++pt) {
            short8 b2 = *reinterpret_cast<const short8*>(sc + (pt * 16 + c) * 80 + g * 16);
            acc2[0][pt] = MFMA(a2_0, b2, acc2[0][pt]);
            acc2[1][pt] = MFMA(a2_1, b2, acc2[1][pt]);
        }
    }
    LGKM0();

    // sigma = H2[o=0][p] -> lane g==0, reg 0
    float sigv[4];
    #pragma unroll
    for (int pt = 0; pt < 4; ++pt) sigv[pt] = acc2[0][pt][0];

    // ---- color MLP in two 32-point chunks, double-bf16
    const uint4v zq = { 0u, 0u, 0u, 0u };
    #pragma unroll
    for (int chunk = 0; chunk < 2; ++chunk) {
        // (a) X2 rows: SH hi/lo (cols 0-15), zeros (cols 48-63); half-wave
        if ((lane >> 5) == chunk) {
            unsigned char* rowh = sc + (lane & 31) * 144;
            unsigned char* rowl = rowh + 4608;
            uint4v h0 = { shq[0], shq[1], shq[2], shq[3] };
            uint4v h1 = { shq[4], shq[5], shq[6], shq[7] };
            uint4v l0 = { shl[0], shl[1], shl[2], shl[3] };
            uint4v l1 = { shl[4], shl[5], shl[6], shl[7] };
            *reinterpret_cast<uint4v*>(rowh +  0) = h0;
            *reinterpret_cast<uint4v*>(rowh + 16) = h1;
            *reinterpret_cast<uint4v*>(rowh + 96) = zq;
            *reinterpret_cast<uint4v*>(rowh +112) = zq;
            *reinterpret_cast<uint4v*>(rowl +  0) = l0;
            *reinterpret_cast<uint4v*>(rowl + 16) = l1;
            *reinterpret_cast<uint4v*>(rowl + 96) = zq;
            *reinterpret_cast<uint4v*>(rowl +112) = zq;
        }
        // (b) X2 cols 16-47 = H2 hi/lo (no relu)
        #pragma unroll
        for (int t = 0; t < 2; ++t)
            #pragma unroll
            for (int pl = 0; pl < 2; ++pl) {
                const int pt = chunk * 2 + pl;
                const float v0 = acc2[t][pt][0], v1 = acc2[t][pt][1];
                const float v2 = acc2[t][pt][2], v3 = acc2[t][pt][3];
                const unsigned h0 = f2bf(v0), h1 = f2bf(v1), h2 = f2bf(v2), h3 = f2bf(v3);
                uint2v qh = { h0 | (h1 << 16), h2 | (h3 << 16) };
                uint2v ql = { pkbf(v0 - bf2f(h0), v1 - bf2f(h1)),
                              pkbf(v2 - bf2f(h2), v3 - bf2f(h3)) };
                *reinterpret_cast<uint2v*>(sc + (pl * 16 + c) * 144 + 32 + 32 * t + 8 * g) = qh;
                *reinterpret_cast<uint2v*>(sc + 4608 + (pl * 16 + c) * 144 + 32 + 32 * t + 8 * g) = ql;
            }
        LGKM0();

        // ---- c1 and c2 layers (identical geometry), double-bf16
        #pragma unroll
        for (int layer = 0; layer < 2; ++layer) {
            const int fb_hi = (layer == 0) ? 16 : 32;
            const int fb_lo = fb_hi + 8;
            short8 bh[2][2], bl[2][2];
            #pragma unroll
            for (int pl = 0; pl < 2; ++pl)
                #pragma unroll
                for (int ks = 0; ks < 2; ++ks) {
                    bh[pl][ks] = *reinterpret_cast<const short8*>(sc + (pl * 16 + c) * 144 + ks * 64 + g * 16);
                    bl[pl][ks] = *reinterpret_cast<const short8*>(sc + 4608 + (pl * 16 + c) * 144 + ks * 64 + g * 16);
                }
            LGKM0();
            #pragma unroll
            for (int ot = 0; ot < 4; ++ot) {
                short8 wh0 = __builtin_bit_cast(short8, wf[(fb_hi + ot * 2 + 0) * 64 + lane]);
                short8 wh1 = __builtin_bit_cast(short8, wf[(fb_hi + ot * 2 + 1) * 64 + lane]);
                short8 wl0 = __builtin_bit_cast(short8, wf[(fb_lo + ot * 2 + 0) * 64 + lane]);
                short8 wl1 = __builtin_bit_cast(short8, wf[(fb_lo + ot * 2 + 1) * 64 + lane]);
                #pragma unroll
                for (int pl = 0; pl < 2; ++pl) {
                    f32x4 d = MFMA(wh0, bh[pl][0], zz);
                    d = MFMA(wh1, bh[pl][1], d);
                    d = MFMA(wh0, bl[pl][0], d);
                    d = MFMA(wh1, bl[pl][1], d);
                    d = MFMA(wl0, bh[pl][0], d);
                    d = MFMA(wl1, bh[pl][1], d);
                    const float e0 = fmaxf(d[0], 0.f), e1 = fmaxf(d[1], 0.f);
                    const float e2 = fmaxf(d[2], 0.f), e3 = fmaxf(d[3], 0.f);
                    const unsigned h0 = f2bf(e0), h1 = f2bf(e1), h2 = f2bf(e2), h3 = f2bf(e3);
                    uint2v qh = { h0 | (h1 << 16), h2 | (h3 << 16) };
                    uint2v ql = { pkbf(e0 - bf2f(h0), e1 - bf2f(h1)),
                                  pkbf(e2 - bf2f(h2), e3 - bf2f(h3)) };
                    *reinterpret_cast<uint2v*>(sc + (pl * 16 + c) * 144 + 32 * ot + 8 * g) = qh;
                    *reinterpret_cast<uint2v*>(sc + 4608 + (pl * 16 + c) * 144 + 32 * ot + 8 * g) = ql;
                }
            }
            LGKM0();
        }

        // ---- c3: H4 @ C3 -> rgb, sigmoid, store
        {
            short8 bh[2][2], bl[2][2];
            #pragma unroll
            for (int pl = 0; pl < 2; ++pl)
                #pragma unroll
                for (int ks = 0; ks < 2; ++ks) {
                    bh[pl][ks] = *reinterpret_cast<const short8*>(sc + (pl * 16 + c) * 144 + ks * 64 + g * 16);
                    bl[pl][ks] = *reinterpret_cast<const short8*>(sc + 4608 + (pl * 16 + c) * 144 + ks * 64 + g * 16);
                }
            LGKM0();
            short8 ch0 = __builtin_bit_cast(short8, wf[(48 + 0) * 64 + lane]);
            short8 ch1 = __builtin_bit_cast(short8, wf[(48 + 1) * 64 + lane]);
            short8 cl0 = __builtin_bit_cast(short8, wf[(50 + 0) * 64 + lane]);
            short8 cl1 = __builtin_bit_cast(short8, wf[(50 + 1) * 64 + lane]);
            #pragma unroll
            for (int pl = 0; pl < 2; ++pl) {
                f32x4 d = MFMA(ch0, bh[pl][0], zz);
                d = MFMA(ch1, bh[pl][1], d);
                d = MFMA(ch0, bl[pl][0], d);
                d = MFMA(ch1, bl[pl][1], d);
                d = MFMA(cl0, bh[pl][0], d);
                d = MFMA(cl1, bh[pl][1], d);
                if (g == 0) {
                    const float r  = 1.f / (1.f + __expf(-d[0]));
                    const float gg = 1.f / (1.f + __expf(-d[1]));
                    const float bb = 1.f / (1.f + __expf(-d[2]));
                    const int pidx = blockIdx.x * 256 + w * 64 + chunk * 32 + pl * 16 + c;
                    float4 o4 = make_float4(r, gg, bb, sigv[chunk * 2 + pl]);
                    *reinterpret_cast<float4*>(out + (size_t)pidx * 4) = o4;
                }
            }
        }
    }
}

extern "C" void kernel_launch(void* const* d_in, const int* in_sizes, int n_in,
                              void* d_out, int out_size, void* d_ws, size_t ws_size,
                              hipStream_t stream) {
    (void)n_in; (void)out_size; (void)ws_size;
    const float* input = (const float*)d_in[0];
    const float* table = (const float*)d_in[1];
    const float* w1    = (const float*)d_in[2];
    const float* w2    = (const float*)d_in[3];
    const float* c1    = (const float*)d_in[4];
    const float* c2    = (const float*)d_in[5];
    const float* c3    = (const float*)d_in[6];
    float* out = (float*)d_out;
    const int N = in_sizes[0] / 6;

    GridParams gp;
    const double pls = exp2(log2(2048.0 * 16.0 / 16.0) / 15.0);
    unsigned dm = 0;
    for (int i = 0; i < LVLS; ++i) {
        const double r = ceil(16.0 * pow(pls, (double)i));
        const long long ri = (long long)r;
        gp.res[i] = (unsigned)ri;
        if (ri * ri * ri <= (long long)TBLN) dm |= (1u << i);
    }
    gp.dense_mask = dm;

    uint4v* wf = (uint4v*)d_ws;  // 52 frags * 64 lanes * 16B = 53248 B
    hipLaunchKernelGGL(prep_frags, dim3(52), dim3(64), 0, stream, w1, w2, c1, c2, c3, wf);
    hipLaunchKernelGGL(nerf_main, dim3(N / 256), dim3(256), 0, stream,
                       input, table, (const uint4v*)wf, out, gp, N);
}

// Round 5
// 312.415 us; speedup vs baseline: 1.9876x; 1.0355x over previous
//
#include <hip/hip_runtime.h>
#include <cmath>

constexpr int LVLS = 16;
constexpr unsigned TBLN = 1u << 19;
constexpr unsigned P1 = 2654435761u;   // multiplies z
constexpr unsigned P2 = 805459861u;    // multiplies y

typedef __attribute__((ext_vector_type(8))) short short8;
typedef __attribute__((ext_vector_type(4))) float f32x4;
typedef __attribute__((ext_vector_type(4))) unsigned uint4v;
typedef __attribute__((ext_vector_type(2))) unsigned uint2v;

struct GridParams { unsigned res[LVLS]; unsigned dense_mask; };

__device__ __host__ __forceinline__ unsigned f2bf(float f) {
    union { float f; unsigned u; } v; v.f = f;
    unsigned u = v.u;
    u += 0x7fffu + ((u >> 16) & 1u);   // RNE
    return u >> 16;
}
__device__ __host__ __forceinline__ float bf2f(unsigned h) {
    union { unsigned u; float f; } v; v.u = h << 16; return v.f;
}
__device__ __forceinline__ unsigned pkbf(float lo, float hi) {
    return f2bf(lo) | (f2bf(hi) << 16);
}
__device__ __forceinline__ float bflo(unsigned u) {
    union { unsigned u; float f; } v; v.u = u << 16; return v.f;
}
__device__ __forceinline__ float bfhi(unsigned u) {
    union { unsigned u; float f; } v; v.u = u & 0xffff0000u; return v.f;
}

#define LGKM0() do { asm volatile("s_waitcnt lgkmcnt(0)" ::: "memory"); \
                     __builtin_amdgcn_sched_barrier(0); } while (0)

#define MFMA(a,b,c) __builtin_amdgcn_mfma_f32_16x16x32_bf16((a),(b),(c),0,0,0)

// ---------------------------------------------------------------------------
// Prep: pack MLP weights into bf16 MFMA A-fragments in d_ws (52 frags).
// f 0..7  : W1 hi | 8..15: W2 hi | 16..23: C1 hi | 24..31: C1 lo
// f 32..39: C2 hi | 40..47: C2 lo | 48..49: C3 hi | 50..51: C3 lo
// ---------------------------------------------------------------------------
__global__ void prep_frags(const float* __restrict__ w1, const float* __restrict__ w2,
                           const float* __restrict__ c1, const float* __restrict__ c2,
                           const float* __restrict__ c3, uint4v* __restrict__ wf) {
    const int f = blockIdx.x;
    const int l = threadIdx.x;
    const int g = l >> 4, c = l & 15;
    float v[8];
    bool lo_part = false;
    if (f < 8) {
        int o = f * 16 + c;
        #pragma unroll
        for (int i = 0; i < 8; ++i) { int k = g * 8 + i; v[i] = w1[k * 128 + o]; }
    } else if (f < 16) {
        int idx = f - 8; int o = (idx >> 2) * 16 + c; int ks = idx & 3;
        #pragma unroll
        for (int i = 0; i < 8; ++i) {
            int k = ks * 32 + g * 8 + i;
            v[i] = (o < 31) ? w2[k * 31 + o] : 0.f;
        }
    } else if (f < 32) {
        int idx = (f - 16) & 7; lo_part = (f >= 24);
        int o = (idx >> 1) * 16 + c; int ks = idx & 1;
        #pragma unroll
        for (int i = 0; i < 8; ++i) {
            int k = ks * 32 + g * 8 + i;
            float x = 0.f;
            if (k < 16) x = c1[k * 64 + o];
            else if (k >= 17 && k <= 46) x = c1[(k - 1) * 64 + o];
            v[i] = x;
        }
    } else if (f < 48) {
        int idx = (f - 32) & 7; lo_part = (f >= 40);
        int o = (idx >> 1) * 16 + c; int ks = idx & 1;
        #pragma unroll
        for (int i = 0; i < 8; ++i) { int k = ks * 32 + g * 8 + i; v[i] = c2[k * 64 + o]; }
    } else {
        int idx = f - 48; lo_part = (idx >= 2); int ks = idx & 1;
        #pragma unroll
        for (int i = 0; i < 8; ++i) {
            int k = ks * 32 + g * 8 + i;
            v[i] = (c < 3) ? c3[k * 3 + c] : 0.f;
        }
    }
    if (lo_part) {
        #pragma unroll
        for (int i = 0; i < 8; ++i) v[i] = v[i] - bf2f(f2bf(v[i]));
    }
    uint4v q = { pkbf(v[0], v[1]), pkbf(v[2], v[3]), pkbf(v[4], v[5]), pkbf(v[6], v[7]) };
    wf[f * 64 + l] = q;
}

// ---------------------------------------------------------------------------
// Table fp32 -> bf16 (one uint = packed f0,f1 per entry)
// ---------------------------------------------------------------------------
__global__ void conv_table(const float* __restrict__ t, unsigned* __restrict__ o, int n2) {
    int i = blockIdx.x * blockDim.x + threadIdx.x;
    const int stride = gridDim.x * blockDim.x;
    for (; i < n2; i += stride) {
        float2 v = reinterpret_cast<const float2*>(t)[i];
        o[i] = pkbf(v.x, v.y);
    }
}

// ---------------------------------------------------------------------------
// One level's trilinear hash-grid lookup (identical math to verified R4 path)
// ---------------------------------------------------------------------------
template<bool BF16T>
__device__ __forceinline__ void enc_level(int lv, float px, float py, float pz,
                                          const GridParams& gp, const void* tblv,
                                          float& ra0, float& ra1)
{
    const unsigned res = gp.res[lv];
    const bool dense = (gp.dense_mask >> lv) & 1u;
    const unsigned rm1 = res - 1u;
    const float rf = (float)res - 1.f;
    const float posx = px * rf, posy = py * rf, posz = pz * rf;
    const float fx = floorf(posx), fy = floorf(posy), fz = floorf(posz);
    const float wx = posx - fx, wy = posy - fy, wz = posz - fz;
    const unsigned x0 = (unsigned)fx, y0 = (unsigned)fy, z0 = (unsigned)fz;
    const unsigned x1 = min(x0 + 1u, rm1), y1 = min(y0 + 1u, rm1), z1 = min(z0 + 1u, rm1);
    const float sx[2] = {1.f - wx, wx}, sy[2] = {1.f - wy, wy}, sz[2] = {1.f - wz, wz};
    unsigned tx[2], ty[2], tz[2];
    if (dense) { tx[0]=x0; tx[1]=x1; ty[0]=y0*res; ty[1]=y1*res; tz[0]=z0*res*res; tz[1]=z1*res*res; }
    else       { tx[0]=x0; tx[1]=x1; ty[0]=y0*P2;  ty[1]=y1*P2;  tz[0]=z0*P1;      tz[1]=z1*P1; }
    float a0 = 0.f, a1 = 0.f;
    if (BF16T) {
        const unsigned* tb = (const unsigned*)tblv + ((size_t)lv << 19);
        if (dense) {
            #pragma unroll
            for (int corner = 0; corner < 8; ++corner) {
                const int ox = (corner >> 2) & 1, oy = (corner >> 1) & 1, oz = corner & 1;
                const unsigned idx = (tx[ox] + ty[oy] + tz[oz]) & (TBLN - 1u);
                const unsigned u = tb[idx];
                const float wc = sx[ox] * sy[oy] * sz[oz];
                a0 += wc * bflo(u); a1 += wc * bfhi(u);
            }
        } else {
            #pragma unroll
            for (int corner = 0; corner < 8; ++corner) {
                const int ox = (corner >> 2) & 1, oy = (corner >> 1) & 1, oz = corner & 1;
                const unsigned idx = (tx[ox] ^ ty[oy] ^ tz[oz]) & (TBLN - 1u);
                const unsigned u = tb[idx];
                const float wc = sx[ox] * sy[oy] * sz[oz];
                a0 += wc * bflo(u); a1 += wc * bfhi(u);
            }
        }
    } else {
        const float* tb = (const float*)tblv + (((size_t)lv << 19) * 2u);
        if (dense) {
            #pragma unroll
            for (int corner = 0; corner < 8; ++corner) {
                const int ox = (corner >> 2) & 1, oy = (corner >> 1) & 1, oz = corner & 1;
                const unsigned idx = (tx[ox] + ty[oy] + tz[oz]) & (TBLN - 1u);
                const float2 f2 = *reinterpret_cast<const float2*>(tb + (size_t)idx * 2u);
                const float wc = sx[ox] * sy[oy] * sz[oz];
                a0 += wc * f2.x; a1 += wc * f2.y;
            }
        } else {
            #pragma unroll
            for (int corner = 0; corner < 8; ++corner) {
                const int ox = (corner >> 2) & 1, oy = (corner >> 1) & 1, oz = corner & 1;
                const unsigned idx = (tx[ox] ^ ty[oy] ^ tz[oz]) & (TBLN - 1u);
                const float2 f2 = *reinterpret_cast<const float2*>(tb + (size_t)idx * 2u);
                const float wc = sx[ox] * sy[oy] * sz[oz];
                a0 += wc * f2.x; a1 += wc * f2.y;
            }
        }
    }
    ra0 = a0; ra1 = a1;
}

// ---------------------------------------------------------------------------
// Gather kernel: grid [8 pairs x C chunks], pair-major (all XCDs share one
// level-pair's table at a time -> L2-resident with bf16 table).
// planes layout: [pair][N] of 8B = {l0f0,l0f1,l1f0,l1f1} bf16.
// ---------------------------------------------------------------------------
template<bool BF16T>
__global__ __launch_bounds__(256, 5)
void gather_pairs(const float* __restrict__ input, const void* __restrict__ tbl,
                  uint2v* __restrict__ planes, GridParams gp, int N)
{
    const int C = N >> 8;
    const int b = blockIdx.x;
    const int pair = b / C;
    const int chunk = b - pair * C;
    const int n = (chunk << 8) + threadIdx.x;

    const float2* ip = reinterpret_cast<const float2*>(input + (size_t)n * 6);
    const float2 iA = ip[0], iB = ip[1];
    const float px = fminf(fmaxf((iA.x + 16.f) * (1.f / 32.f), 0.f), 1.f);
    const float py = fminf(fmaxf((iA.y + 16.f) * (1.f / 32.f), 0.f), 1.f);
    const float pz = fminf(fmaxf((iB.x + 16.f) * (1.f / 32.f), 0.f), 1.f);

    float a00, a01, a10, a11;
    enc_level<BF16T>(2 * pair + 0, px, py, pz, gp, tbl, a00, a01);
    enc_level<BF16T>(2 * pair + 1, px, py, pz, gp, tbl, a10, a11);

    uint2v q = { pkbf(a00, a01), pkbf(a10, a11) };
    planes[(size_t)pair * N + n] = q;
}

// ---------------------------------------------------------------------------
// MLP kernel: R4's verified MFMA pipeline; B-fragments from planes.
// Per-wave LDS 9216 B as in R4.
// ---------------------------------------------------------------------------
__global__ __launch_bounds__(256)
void nerf_mlp(const float* __restrict__ input, const uint2v* __restrict__ planes,
              const uint4v* __restrict__ wf, float* __restrict__ out, int N)
{
    __shared__ unsigned char smem[4 * 9216];
    const int tid  = threadIdx.x;
    const int lane = tid & 63;
    const int w    = tid >> 6;
    const int g    = lane >> 4, c = lane & 15;
    unsigned char* const sc = smem + w * 9216;

    const int n = blockIdx.x * 256 + tid;
    const int pbase = blockIdx.x * 256 + w * 64;

    const float2* ip = reinterpret_cast<const float2*>(input + (size_t)n * 6);
    const float2 iB = ip[1], iC = ip[2];

    // ---- SH degree 4, hi/lo packed in regs
    unsigned shq[8], shl[8];
    {
        const float x = iB.y, y = iC.x, z = iC.y;
        const float x2 = x*x, y2 = y*y, z2 = z*z;
        const float xy = x*y, yz = y*z, xz = x*z;
        float s[16];
        s[0]  = 0.28209479177387814f;
        s[1]  = -0.48860251190291987f * y;
        s[2]  =  0.48860251190291987f * z;
        s[3]  = -0.48860251190291987f * x;
        s[4]  =  1.0925484305920792f * xy;
        s[5]  = -1.0925484305920792f * yz;
        s[6]  =  0.94617469575756f * z2 - 0.31539156525252005f;
        s[7]  = -1.0925484305920792f * xz;
        s[8]  =  0.5462742152960396f * (x2 - y2);
        s[9]  =  0.5900435899266435f * y * (-3.0f * x2 + y2);
        s[10] =  2.890611442640554f * xy * z;
        s[11] =  0.4570457994644657f * y * (1.0f - 5.0f * z2);
        s[12] =  0.3731763325901154f * z * (5.0f * z2 - 3.0f);
        s[13] =  0.4570457994644657f * x * (1.0f - 5.0f * z2);
        s[14] =  1.445305721320277f * z * (x2 - y2);
        s[15] =  0.5900435899266435f * x * (-x2 + 3.0f * y2);
        #pragma unroll
        for (int i = 0; i < 8; ++i) {
            unsigned h0 = f2bf(s[2*i]), h1 = f2bf(s[2*i+1]);
            shq[i] = h0 | (h1 << 16);
            shl[i] = pkbf(s[2*i] - bf2f(h0), s[2*i+1] - bf2f(h1));
        }
    }

    const f32x4 zz = {0.f, 0.f, 0.f, 0.f};

    // ---- B-fragments straight from planes (k = 8g..8g+7 -> planes 2g, 2g+1)
    short8 xb[4];
    #pragma unroll
    for (int pt = 0; pt < 4; ++pt) {
        const int p = pbase + pt * 16 + c;
        uint2v q0 = planes[(size_t)(2 * g)     * N + p];
        uint2v q1 = planes[(size_t)(2 * g + 1) * N + p];
        uint4v t = { q0.x, q0.y, q1.x, q1.y };
        xb[pt] = __builtin_bit_cast(short8, t);
    }

    // ---- sigma MLP: L1 (32->128, relu) + L2 (128->32), plain bf16
    f32x4 acc2[2][4];
    #pragma unroll
    for (int t = 0; t < 2; ++t)
        #pragma unroll
        for (int pt = 0; pt < 4; ++pt) acc2[t][pt] = zz;

    #pragma unroll
    for (int oc = 0; oc < 4; ++oc) {
        short8 a1_0 = __builtin_bit_cast(short8, wf[(2 * oc + 0) * 64 + lane]);
        short8 a1_1 = __builtin_bit_cast(short8, wf[(2 * oc + 1) * 64 + lane]);
        f32x4 d1[2][4];
        #pragma unroll
        for (int pt = 0; pt < 4; ++pt) {
            d1[0][pt] = MFMA(a1_0, xb[pt], zz);
            d1[1][pt] = MFMA(a1_1, xb[pt], zz);
        }
        #pragma unroll
        for (int t = 0; t < 2; ++t)
            #pragma unroll
            for (int pt = 0; pt < 4; ++pt) {
                const float e0 = fmaxf(d1[t][pt][0], 0.f), e1 = fmaxf(d1[t][pt][1], 0.f);
                const float e2 = fmaxf(d1[t][pt][2], 0.f), e3 = fmaxf(d1[t][pt][3], 0.f);
                uint2v q = { pkbf(e0, e1), pkbf(e2, e3) };
                *reinterpret_cast<uint2v*>(sc + (pt * 16 + c) * 80 + 32 * t + 8 * g) = q;
            }
        LGKM0();
        short8 a2_0 = __builtin_bit_cast(short8, wf[(8 + 0 * 4 + oc) * 64 + lane]);
        short8 a2_1 = __builtin_bit_cast(short8, wf[(8 + 1 * 4 + oc) * 64 + lane]);
        #pragma unroll
        for (int pt = 0; pt < 4; ++pt) {
            short8 b2 = *reinterpret_cast<const short8*>(sc + (pt * 16 + c) * 80 + g * 16);
            acc2[0][pt] = MFMA(a2_0, b2, acc2[0][pt]);
            acc2[1][pt] = MFMA(a2_1, b2, acc2[1][pt]);
        }
    }
    LGKM0();

    float sigv[4];
    #pragma unroll
    for (int pt = 0; pt < 4; ++pt) sigv[pt] = acc2[0][pt][0];

    // ---- color MLP in two 32-point chunks, double-bf16
    const uint4v zq = { 0u, 0u, 0u, 0u };
    #pragma unroll
    for (int chunk = 0; chunk < 2; ++chunk) {
        if ((lane >> 5) == chunk) {
            unsigned char* rowh = sc + (lane & 31) * 144;
            unsigned char* rowl = rowh + 4608;
            uint4v h0 = { shq[0], shq[1], shq[2], shq[3] };
            uint4v h1 = { shq[4], shq[5], shq[6], shq[7] };
            uint4v l0 = { shl[0], shl[1], shl[2], shl[3] };
            uint4v l1 = { shl[4], shl[5], shl[6], shl[7] };
            *reinterpret_cast<uint4v*>(rowh +  0) = h0;
            *reinterpret_cast<uint4v*>(rowh + 16) = h1;
            *reinterpret_cast<uint4v*>(rowh + 96) = zq;
            *reinterpret_cast<uint4v*>(rowh +112) = zq;
            *reinterpret_cast<uint4v*>(rowl +  0) = l0;
            *reinterpret_cast<uint4v*>(rowl + 16) = l1;
            *reinterpret_cast<uint4v*>(rowl + 96) = zq;
            *reinterpret_cast<uint4v*>(rowl +112) = zq;
        }
        #pragma unroll
        for (int t = 0; t < 2; ++t)
            #pragma unroll
            for (int pl = 0; pl < 2; ++pl) {
                const int pt = chunk * 2 + pl;
                const float v0 = acc2[t][pt][0], v1 = acc2[t][pt][1];
                const float v2 = acc2[t][pt][2], v3 = acc2[t][pt][3];
                const unsigned h0 = f2bf(v0), h1 = f2bf(v1), h2 = f2bf(v2), h3 = f2bf(v3);
                uint2v qh = { h0 | (h1 << 16), h2 | (h3 << 16) };
                uint2v ql = { pkbf(v0 - bf2f(h0), v1 - bf2f(h1)),
                              pkbf(v2 - bf2f(h2), v3 - bf2f(h3)) };
                *reinterpret_cast<uint2v*>(sc + (pl * 16 + c) * 144 + 32 + 32 * t + 8 * g) = qh;
                *reinterpret_cast<uint2v*>(sc + 4608 + (pl * 16 + c) * 144 + 32 + 32 * t + 8 * g) = ql;
            }
        LGKM0();

        #pragma unroll
        for (int layer = 0; layer < 2; ++layer) {
            const int fb_hi = (layer == 0) ? 16 : 32;
            const int fb_lo = fb_hi + 8;
            short8 bh[2][2], bl[2][2];
            #pragma unroll
            for (int pl = 0; pl < 2; ++pl)
                #pragma unroll
                for (int ks = 0; ks < 2; ++ks) {
                    bh[pl][ks] = *reinterpret_cast<const short8*>(sc + (pl * 16 + c) * 144 + ks * 64 + g * 16);
                    bl[pl][ks] = *reinterpret_cast<const short8*>(sc + 4608 + (pl * 16 + c) * 144 + ks * 64 + g * 16);
                }
            LGKM0();
            #pragma unroll
            for (int ot = 0; ot < 4; ++ot) {
                short8 wh0 = __builtin_bit_cast(short8, wf[(fb_hi + ot * 2 + 0) * 64 + lane]);
                short8 wh1 = __builtin_bit_cast(short8, wf[(fb_hi + ot * 2 + 1) * 64 + lane]);
                short8 wl0 = __builtin_bit_cast(short8, wf[(fb_lo + ot * 2 + 0) * 64 + lane]);
                short8 wl1 = __builtin_bit_cast(short8, wf[(fb_lo + ot * 2 + 1) * 64 + lane]);
                #pragma unroll
                for (int pl = 0; pl < 2; ++pl) {
                    f32x4 d = MFMA(wh0, bh[pl][0], zz);
                    d = MFMA(wh1, bh[pl][1], d);
                    d = MFMA(wh0, bl[pl][0], d);
                    d = MFMA(wh1, bl[pl][1], d);
                    d = MFMA(wl0, bh[pl][0], d);
                    d = MFMA(wl1, bh[pl][1], d);
                    const float e0 = fmaxf(d[0], 0.f), e1 = fmaxf(d[1], 0.f);
                    const float e2 = fmaxf(d[2], 0.f), e3 = fmaxf(d[3], 0.f);
                    const unsigned h0 = f2bf(e0), h1 = f2bf(e1), h2 = f2bf(e2), h3 = f2bf(e3);
                    uint2v qh = { h0 | (h1 << 16), h2 | (h3 << 16) };
                    uint2v ql = { pkbf(e0 - bf2f(h0), e1 - bf2f(h1)),
                                  pkbf(e2 - bf2f(h2), e3 - bf2f(h3)) };
                    *reinterpret_cast<uint2v*>(sc + (pl * 16 + c) * 144 + 32 * ot + 8 * g) = qh;
                    *reinterpret_cast<uint2v*>(sc + 4608 + (pl * 16 + c) * 144 + 32 * ot + 8 * g) = ql;
                }
            }
            LGKM0();
        }

        {
            short8 bh[2][2], bl[2][2];
            #pragma unroll
            for (int pl = 0; pl < 2; ++pl)
                #pragma unroll
                for (int ks = 0; ks < 2; ++ks) {
                    bh[pl][ks] = *reinterpret_cast<const short8*>(sc + (pl * 16 + c) * 144 + ks * 64 + g * 16);
                    bl[pl][ks] = *reinterpret_cast<const short8*>(sc + 4608 + (pl * 16 + c) * 144 + ks * 64 + g * 16);
                }
            LGKM0();
            short8 ch0 = __builtin_bit_cast(short8, wf[(48 + 0) * 64 + lane]);
            short8 ch1 = __builtin_bit_cast(short8, wf[(48 + 1) * 64 + lane]);
            short8 cl0 = __builtin_bit_cast(short8, wf[(50 + 0) * 64 + lane]);
            short8 cl1 = __builtin_bit_cast(short8, wf[(50 + 1) * 64 + lane]);
            #pragma unroll
            for (int pl = 0; pl < 2; ++pl) {
                f32x4 d = MFMA(ch0, bh[pl][0], zz);
                d = MFMA(ch1, bh[pl][1], d);
                d = MFMA(ch0, bl[pl][0], d);
                d = MFMA(ch1, bl[pl][1], d);
                d = MFMA(cl0, bh[pl][0], d);
                d = MFMA(cl1, bh[pl][1], d);
                if (g == 0) {
                    const float r  = 1.f / (1.f + __expf(-d[0]));
                    const float gg = 1.f / (1.f + __expf(-d[1]));
                    const float bb = 1.f / (1.f + __expf(-d[2]));
                    const int pidx = blockIdx.x * 256 + w * 64 + chunk * 32 + pl * 16 + c;
                    float4 o4 = make_float4(r, gg, bb, sigv[chunk * 2 + pl]);
                    *reinterpret_cast<float4*>(out + (size_t)pidx * 4) = o4;
                }
            }
        }
    }
}

// ---------------------------------------------------------------------------
// Fallback: R4's fused kernel (used only if ws_size is too small for planes)
// ---------------------------------------------------------------------------
__global__ __launch_bounds__(256)
void nerf_fused(const float* __restrict__ input, const float* __restrict__ table,
                const uint4v* __restrict__ wf, float* __restrict__ out,
                GridParams gp, int N)
{
    __shared__ unsigned char smem[4 * 9216];
    const int tid  = threadIdx.x;
    const int lane = tid & 63;
    const int w    = tid >> 6;
    const int g    = lane >> 4, c = lane & 15;
    unsigned char* const sc = smem + w * 9216;

    const int n = blockIdx.x * 256 + tid;
    const float2* ip = reinterpret_cast<const float2*>(input + (size_t)n * 6);
    const float2 iA = ip[0], iB = ip[1], iC = ip[2];
    const float px = fminf(fmaxf((iA.x + 16.f) * (1.f / 32.f), 0.f), 1.f);
    const float py = fminf(fmaxf((iA.y + 16.f) * (1.f / 32.f), 0.f), 1.f);
    const float pz = fminf(fmaxf((iB.x + 16.f) * (1.f / 32.f), 0.f), 1.f);

    for (int lo = 0; lo < 4; ++lo) {
        unsigned pk4[4];
        #pragma unroll
        for (int li = 0; li < 4; ++li) {
            float a0, a1;
            enc_level<false>(lo * 4 + li, px, py, pz, gp, (const void*)table, a0, a1);
            pk4[li] = pkbf(a0, a1);
        }
        uint4v q = { pk4[0], pk4[1], pk4[2], pk4[3] };
        *reinterpret_cast<uint4v*>(sc + lane * 80 + lo * 16) = q;
    }

    unsigned shq[8], shl[8];
    {
        const float x = iB.y, y = iC.x, z = iC.y;
        const float x2 = x*x, y2 = y*y, z2 = z*z;
        const float xy = x*y, yz = y*z, xz = x*z;
        float s[16];
        s[0]  = 0.28209479177387814f;
        s[1]  = -0.48860251190291987f * y;
        s[2]  =  0.48860251190291987f * z;
        s[3]  = -0.48860251190291987f * x;
        s[4]  =  1.0925484305920792f * xy;
        s[5]  = -1.0925484305920792f * yz;
        s[6]  =  0.94617469575756f * z2 - 0.31539156525252005f;
        s[7]  = -1.0925484305920792f * xz;
        s[8]  =  0.5462742152960396f * (x2 - y2);
        s[9]  =  0.5900435899266435f * y * (-3.0f * x2 + y2);
        s[10] =  2.890611442640554f * xy * z;
        s[11] =  0.4570457994644657f * y * (1.0f - 5.0f * z2);
        s[12] =  0.3731763325901154f * z * (5.0f * z2 - 3.0f);
        s[13] =  0.4570457994644657f * x * (1.0f - 5.0f * z2);
        s[14] =  1.445305721320277f * z * (x2 - y2);
        s[15] =  0.5900435899266435f * x * (-x2 + 3.0f * y2);
        #pragma unroll
        for (int i = 0; i < 8; ++i) {
            unsigned h0 = f2bf(s[2*i]), h1 = f2bf(s[2*i+1]);
            shq[i] = h0 | (h1 << 16);
            shl[i] = pkbf(s[2*i] - bf2f(h0), s[2*i+1] - bf2f(h1));
        }
    }
    LGKM0();

    const f32x4 zz = {0.f, 0.f, 0.f, 0.f};
    short8 xb[4];
    #pragma unroll
    for (int pt = 0; pt < 4; ++pt)
        xb[pt] = *reinterpret_cast<const short8*>(sc + (pt * 16 + c) * 80 + g * 16);

    f32x4 acc2[2][4];
    #pragma unroll
    for (int t = 0; t < 2; ++t)
        #pragma unroll
        for (int pt = 0; pt < 4; ++pt) acc2[t][pt] = zz;

    #pragma unroll
    for (int oc = 0; oc < 4; ++oc) {
        short8 a1_0 = __builtin_bit_cast(short8, wf[(2 * oc + 0) * 64 + lane]);
        short8 a1_1 = __builtin_bit_cast(short8, wf[(2 * oc + 1) * 64 + lane]);
        f32x4 d1[2][4];
        #pragma unroll
        for (int pt = 0; pt < 4; ++pt) {
            d1[0][pt] = MFMA(a1_0, xb[pt], zz);
            d1[1][pt] = MFMA(a1_1, xb[pt], zz);
        }
        #pragma unroll
        for (int t = 0; t < 2; ++t)
            #pragma unroll
            for (int pt = 0; pt < 4; ++pt) {
                const float e0 = fmaxf(d1[t][pt][0], 0.f), e1 = fmaxf(d1[t][pt][1], 0.f);
                const float e2 = fmaxf(d1[t][pt][2], 0.f), e3 = fmaxf(d1[t][pt][3], 0.f);
                uint2v q = { pkbf(e0, e1), pkbf(e2, e3) };
                *reinterpret_cast<uint2v*>(sc + (pt * 16 + c) * 80 + 32 * t + 8 * g) = q;
            }
        LGKM0();
        short8 a2_0 = __builtin_bit_cast(short8, wf[(8 + 0 * 4 + oc) * 64 + lane]);
        short8 a2_1 = __builtin_bit_cast(short8, wf[(8 + 1 * 4 + oc) * 64 + lane]);
        #pragma unroll
        for (int pt = 0; pt < 4; ++pt) {
            short8 b2 = *reinterpret_cast<const short8*>(sc + (pt * 16 + c) * 80 + g * 16);
            acc2[0][pt] = MFMA(a2_0, b2, acc2[0][pt]);
            acc2[1][pt] = MFMA(a2_1, b2, acc2[1][pt]);
        }
    }
    LGKM0();

    float sigv[4];
    #pragma unroll
    for (int pt = 0; pt < 4; ++pt) sigv[pt] = acc2[0][pt][0];

    const uint4v zq = { 0u, 0u, 0u, 0u };
    #pragma unroll
    for (int chunk = 0; chunk < 2; ++chunk) {
        if ((lane >> 5) == chunk) {
            unsigned char* rowh = sc + (lane & 31) * 144;
            unsigned char* rowl = rowh + 4608;
            uint4v h0 = { shq[0], shq[1], shq[2], shq[3] };
            uint4v h1 = { shq[4], shq[5], shq[6], shq[7] };
            uint4v l0 = { shl[0], shl[1], shl[2], shl[3] };
            uint4v l1 = { shl[4], shl[5], shl[6], shl[7] };
            *reinterpret_cast<uint4v*>(rowh +  0) = h0;
            *reinterpret_cast<uint4v*>(rowh + 16) = h1;
            *reinterpret_cast<uint4v*>(rowh + 96) = zq;
            *reinterpret_cast<uint4v*>(rowh +112) = zq;
            *reinterpret_cast<uint4v*>(rowl +  0) = l0;
            *reinterpret_cast<uint4v*>(rowl + 16) = l1;
            *reinterpret_cast<uint4v*>(rowl + 96) = zq;
            *reinterpret_cast<uint4v*>(rowl +112) = zq;
        }
        #pragma unroll
        for (int t = 0; t < 2; ++t)
            #pragma unroll
            for (int pl = 0; pl < 2; ++pl) {
                const int pt = chunk * 2 + pl;
                const float v0 = acc2[t][pt][0], v1 = acc2[t][pt][1];
                const float v2 = acc2[t][pt][2], v3 = acc2[t][pt][3];
                const unsigned h0 = f2bf(v0), h1 = f2bf(v1), h2 = f2bf(v2), h3 = f2bf(v3);
                uint2v qh = { h0 | (h1 << 16), h2 | (h3 << 16) };
                uint2v ql = { pkbf(v0 - bf2f(h0), v1 - bf2f(h1)),
                              pkbf(v2 - bf2f(h2), v3 - bf2f(h3)) };
                *reinterpret_cast<uint2v*>(sc + (pl * 16 + c) * 144 + 32 + 32 * t + 8 * g) = qh;
                *reinterpret_cast<uint2v*>(sc + 4608 + (pl * 16 + c) * 144 + 32 + 32 * t + 8 * g) = ql;
            }
        LGKM0();

        #pragma unroll
        for (int layer = 0; layer < 2; ++layer) {
            const int fb_hi = (layer == 0) ? 16 : 32;
            const int fb_lo = fb_hi + 8;
            short8 bh[2][2], bl[2][2];
            #pragma unroll
            for (int pl = 0; pl < 2; ++pl)
                #pragma unroll
                for (int ks = 0; ks < 2; ++ks) {
                    bh[pl][ks] = *reinterpret_cast<const short8*>(sc + (pl * 16 + c) * 144 + ks * 64 + g * 16);
                    bl[pl][ks] = *reinterpret_cast<const short8*>(sc + 4608 + (pl * 16 + c) * 144 + ks * 64 + g * 16);
                }
            LGKM0();
            #pragma unroll
            for (int ot = 0; ot < 4; ++ot) {
                short8 wh0 = __builtin_bit_cast(short8, wf[(fb_hi + ot * 2 + 0) * 64 + lane]);
                short8 wh1 = __builtin_bit_cast(short8, wf[(fb_hi + ot * 2 + 1) * 64 + lane]);
                short8 wl0 = __builtin_bit_cast(short8, wf[(fb_lo + ot * 2 + 0) * 64 + lane]);
                short8 wl1 = __builtin_bit_cast(short8, wf[(fb_lo + ot * 2 + 1) * 64 + lane]);
                #pragma unroll
                for (int pl = 0; pl < 2; ++pl) {
                    f32x4 d = MFMA(wh0, bh[pl][0], zz);
                    d = MFMA(wh1, bh[pl][1], d);
                    d = MFMA(wh0, bl[pl][0], d);
                    d = MFMA(wh1, bl[pl][1], d);
                    d = MFMA(wl0, bh[pl][0], d);
                    d = MFMA(wl1, bh[pl][1], d);
                    const float e0 = fmaxf(d[0], 0.f), e1 = fmaxf(d[1], 0.f);
                    const float e2 = fmaxf(d[2], 0.f), e3 = fmaxf(d[3], 0.f);
                    const unsigned h0 = f2bf(e0), h1 = f2bf(e1), h2 = f2bf(e2), h3 = f2bf(e3);
                    uint2v qh = { h0 | (h1 << 16), h2 | (h3 << 16) };
                    uint2v ql = { pkbf(e0 - bf2f(h0), e1 - bf2f(h1)),
                                  pkbf(e2 - bf2f(h2), e3 - bf2f(h3)) };
                    *reinterpret_cast<uint2v*>(sc + (pl * 16 + c) * 144 + 32 * ot + 8 * g) = qh;
                    *reinterpret_cast<uint2v*>(sc + 4608 + (pl * 16 + c) * 144 + 32 * ot + 8 * g) = ql;
                }
            }
            LGKM0();
        }

        {
            short8 bh[2][2], bl[2][2];
            #pragma unroll
            for (int pl = 0; pl < 2; ++pl)
                #pragma unroll
                for (int ks = 0; ks < 2; ++ks) {
                    bh[pl][ks] = *reinterpret_cast<const short8*>(sc + (pl * 16 + c) * 144 + ks * 64 + g * 16);
                    bl[pl][ks] = *reinterpret_cast<const short8*>(sc + 4608 + (pl * 16 + c) * 144 + ks * 64 + g * 16);
                }
            LGKM0();
            short8 ch0 = __builtin_bit_cast(short8, wf[(48 + 0) * 64 + lane]);
            short8 ch1 = __builtin_bit_cast(short8, wf[(48 + 1) * 64 + lane]);
            short8 cl0 = __builtin_bit_cast(short8, wf[(50 + 0) * 64 + lane]);
            short8 cl1 = __builtin_bit_cast(short8, wf[(50 + 1) * 64 + lane]);
            #pragma unroll
            for (int pl = 0; pl < 2; ++pl) {
                f32x4 d = MFMA(ch0, bh[pl][0], zz);
                d = MFMA(ch1, bh[pl][1], d);
                d = MFMA(ch0, bl[pl][0], d);
                d = MFMA(ch1, bl[pl][1], d);
                d = MFMA(cl0, bh[pl][0], d);
                d = MFMA(cl1, bh[pl][1], d);
                if (g == 0) {
                    const float r  = 1.f / (1.f + __expf(-d[0]));
                    const float gg = 1.f / (1.f + __expf(-d[1]));
                    const float bb = 1.f / (1.f + __expf(-d[2]));
                    const int pidx = blockIdx.x * 256 + w * 64 + chunk * 32 + pl * 16 + c;
                    float4 o4 = make_float4(r, gg, bb, sigv[chunk * 2 + pl]);
                    *reinterpret_cast<float4*>(out + (size_t)pidx * 4) = o4;
                }
            }
        }
    }
}

extern "C" void kernel_launch(void* const* d_in, const int* in_sizes, int n_in,
                              void* d_out, int out_size, void* d_ws, size_t ws_size,
                              hipStream_t stream) {
    (void)n_in; (void)out_size;
    const float* input = (const float*)d_in[0];
    const float* table = (const float*)d_in[1];
    const float* w1    = (const float*)d_in[2];
    const float* w2    = (const float*)d_in[3];
    const float* c1    = (const float*)d_in[4];
    const float* c2    = (const float*)d_in[5];
    const float* c3    = (const float*)d_in[6];
    float* out = (float*)d_out;
    const int N = in_sizes[0] / 6;

    GridParams gp;
    const double pls = exp2(log2(2048.0 * 16.0 / 16.0) / 15.0);
    unsigned dm = 0;
    for (int i = 0; i < LVLS; ++i) {
        const double r = ceil(16.0 * pow(pls, (double)i));
        const long long ri = (long long)r;
        gp.res[i] = (unsigned)ri;
        if (ri * ri * ri <= (long long)TBLN) dm |= (1u << i);
    }
    gp.dense_mask = dm;

    const size_t FRAGS_B  = 52 * 64 * 16;                 // 53248
    const size_t PLANES_B = (size_t)8 * (size_t)N * 8;    // 33.5 MB
    const size_t TB16_B   = (size_t)LVLS * TBLN * 4;      // 33.5 MB
    char* base = (char*)d_ws;
    uint4v* wf = (uint4v*)d_ws;
    const int C = N / 256;

    hipLaunchKernelGGL(prep_frags, dim3(52), dim3(64), 0, stream, w1, w2, c1, c2, c3, wf);

    if (ws_size >= FRAGS_B + PLANES_B + TB16_B) {
        uint2v* planes = (uint2v*)(base + FRAGS_B);
        unsigned* tb16 = (unsigned*)(base + FRAGS_B + PLANES_B);
        hipLaunchKernelGGL(conv_table, dim3(2048), dim3(256), 0, stream,
                           table, tb16, (int)(LVLS * TBLN));
        hipLaunchKernelGGL(gather_pairs<true>, dim3(8 * C), dim3(256), 0, stream,
                           input, (const void*)tb16, planes, gp, N);
        hipLaunchKernelGGL(nerf_mlp, dim3(C), dim3(256), 0, stream,
                           input, (const uint2v*)planes, (const uint4v*)wf, out, N);
    } else if (ws_size >= FRAGS_B + PLANES_B) {
        uint2v* planes = (uint2v*)(base + FRAGS_B);
        hipLaunchKernelGGL(gather_pairs<false>, dim3(8 * C), dim3(256), 0, stream,
                           input, (const void*)table, planes, gp, N);
        hipLaunchKernelGGL(nerf_mlp, dim3(C), dim3(256), 0, stream,
                           input, (const uint2v*)planes, (const uint4v*)wf, out, N);
    } else {
        hipLaunchKernelGGL(nerf_fused, dim3(C), dim3(256), 0, stream,
                           input, table, (const uint4v*)wf, out, gp, N);
    }
}

// Round 8
// 281.804 us; speedup vs baseline: 2.2035x; 1.1086x over previous
//
#include <hip/hip_runtime.h>
#include <cmath>

constexpr int LVLS = 16;
constexpr unsigned TBLN = 1u << 19;
constexpr unsigned P1 = 2654435761u;   // multiplies z
constexpr unsigned P2 = 805459861u;    // multiplies y

typedef __attribute__((ext_vector_type(8))) short short8;
typedef __attribute__((ext_vector_type(4))) float f32x4;
typedef __attribute__((ext_vector_type(4))) unsigned uint4v;
typedef __attribute__((ext_vector_type(2))) unsigned uint2v;

struct GridParams { unsigned res[LVLS]; unsigned dense_mask; };

__device__ __host__ __forceinline__ unsigned f2bf(float f) {
    union { float f; unsigned u; } v; v.f = f;
    unsigned u = v.u;
    u += 0x7fffu + ((u >> 16) & 1u);   // RNE
    return u >> 16;
}
__device__ __host__ __forceinline__ float bf2f(unsigned h) {
    union { unsigned u; float f; } v; v.u = h << 16; return v.f;
}
__device__ __forceinline__ unsigned pkbf(float lo, float hi) {
    return f2bf(lo) | (f2bf(hi) << 16);
}

#define LGKM0() do { asm volatile("s_waitcnt lgkmcnt(0)" ::: "memory"); \
                     __builtin_amdgcn_sched_barrier(0); } while (0)

#define MFMA(a,b,c) __builtin_amdgcn_mfma_f32_16x16x32_bf16((a),(b),(c),0,0,0)

__device__ __forceinline__ void load_pos(const float* __restrict__ input, int n,
                                         float& px, float& py, float& pz) {
    const float2* ip = reinterpret_cast<const float2*>(input + (size_t)n * 6);
    const float2 iA = ip[0], iB = ip[1];
    px = fminf(fmaxf((iA.x + 16.f) * (1.f / 32.f), 0.f), 1.f);
    py = fminf(fmaxf((iA.y + 16.f) * (1.f / 32.f), 0.f), 1.f);
    pz = fminf(fmaxf((iB.x + 16.f) * (1.f / 32.f), 0.f), 1.f);
}

// ---------------------------------------------------------------------------
// Prep: pack MLP weights into bf16 MFMA A-fragments (52 frags) — verified R4/R5
// f 0..7: W1 hi | 8..15: W2 hi | 16..23: C1 hi | 24..31: C1 lo
// f 32..39: C2 hi | 40..47: C2 lo | 48..49: C3 hi | 50..51: C3 lo
// ---------------------------------------------------------------------------
__global__ void prep_frags(const float* __restrict__ w1, const float* __restrict__ w2,
                           const float* __restrict__ c1, const float* __restrict__ c2,
                           const float* __restrict__ c3, uint4v* __restrict__ wf) {
    const int f = blockIdx.x;
    const int l = threadIdx.x;
    const int g = l >> 4, c = l & 15;
    float v[8];
    bool lo_part = false;
    if (f < 8) {
        int o = f * 16 + c;
        #pragma unroll
        for (int i = 0; i < 8; ++i) { int k = g * 8 + i; v[i] = w1[k * 128 + o]; }
    } else if (f < 16) {
        int idx = f - 8; int o = (idx >> 2) * 16 + c; int ks = idx & 3;
        #pragma unroll
        for (int i = 0; i < 8; ++i) {
            int k = ks * 32 + g * 8 + i;
            v[i] = (o < 31) ? w2[k * 31 + o] : 0.f;
        }
    } else if (f < 32) {
        int idx = (f - 16) & 7; lo_part = (f >= 24);
        int o = (idx >> 1) * 16 + c; int ks = idx & 1;
        #pragma unroll
        for (int i = 0; i < 8; ++i) {
            int k = ks * 32 + g * 8 + i;
            float x = 0.f;
            if (k < 16) x = c1[k * 64 + o];
            else if (k >= 17 && k <= 46) x = c1[(k - 1) * 64 + o];
            v[i] = x;
        }
    } else if (f < 48) {
        int idx = (f - 32) & 7; lo_part = (f >= 40);
        int o = (idx >> 1) * 16 + c; int ks = idx & 1;
        #pragma unroll
        for (int i = 0; i < 8; ++i) { int k = ks * 32 + g * 8 + i; v[i] = c2[k * 64 + o]; }
    } else {
        int idx = f - 48; lo_part = (idx >= 2); int ks = idx & 1;
        #pragma unroll
        for (int i = 0; i < 8; ++i) {
            int k = ks * 32 + g * 8 + i;
            v[i] = (c < 3) ? c3[k * 3 + c] : 0.f;
        }
    }
    if (lo_part) {
        #pragma unroll
        for (int i = 0; i < 8; ++i) v[i] = v[i] - bf2f(f2bf(v[i]));
    }
    uint4v q = { pkbf(v[0], v[1]), pkbf(v[2], v[3]), pkbf(v[4], v[5]), pkbf(v[6], v[7]) };
    wf[f * 64 + l] = q;
}

// ---------------------------------------------------------------------------
// int8 table pipeline: zero scales -> per-level absmax -> quantize
// ---------------------------------------------------------------------------
__global__ void zero16(unsigned* __restrict__ scl) {
    if (threadIdx.x < 16) scl[threadIdx.x] = 0u;
}

__global__ void absmax_lvl(const float* __restrict__ t, unsigned* __restrict__ scl) {
    __shared__ float red[256];
    const int tid = threadIdx.x;
    const int lv = blockIdx.x >> 5;
    const int ch = blockIdx.x & 31;
    // per level: 2*TBLN floats; per chunk: 32768 floats = 8192 float4
    const float4* p = reinterpret_cast<const float4*>(
        t + (size_t)lv * TBLN * 2u + (size_t)ch * 32768u);
    float m = 0.f;
    for (int i = tid; i < 8192; i += 256) {
        const float4 v = p[i];
        m = fmaxf(m, fmaxf(fmaxf(fabsf(v.x), fabsf(v.y)), fmaxf(fabsf(v.z), fabsf(v.w))));
    }
    red[tid] = m;
    __syncthreads();
    for (int s = 128; s > 0; s >>= 1) {
        if (tid < s) red[tid] = fmaxf(red[tid], red[tid + s]);
        __syncthreads();
    }
    if (tid == 0) atomicMax(&scl[lv], __float_as_uint(red[0]));  // positive-float bits: monotonic
}

__global__ void quant_table(const float* __restrict__ t, const unsigned* __restrict__ scl,
                            unsigned short* __restrict__ o) {
    const int n = LVLS * (int)TBLN;
    int i = blockIdx.x * 256 + threadIdx.x;
    const int stride = gridDim.x * 256;
    for (; i < n; i += stride) {
        const int lv = i >> 19;
        const float scale = __uint_as_float(scl[lv]);
        const float inv = (scale > 0.f) ? (127.f / scale) : 0.f;
        const float2 v = reinterpret_cast<const float2*>(t)[i];
        const int q0 = (int)rintf(v.x * inv);
        const int q1 = (int)rintf(v.y * inv);
        o[i] = (unsigned short)((q0 & 0xFF) | ((q1 & 0xFF) << 8));
    }
}

// ---------------------------------------------------------------------------
// Trilinear hash-grid lookup — int8 table variant (raw integer accumulation;
// scale applied once at the end by the caller: interpolation is linear).
// ---------------------------------------------------------------------------
__device__ __forceinline__ void enc_s8(int lv, float px, float py, float pz,
                                       const GridParams& gp,
                                       const unsigned short* __restrict__ tb8,
                                       float& ra0, float& ra1)
{
    const unsigned res = gp.res[lv];
    const bool dense = (gp.dense_mask >> lv) & 1u;
    const unsigned rm1 = res - 1u;
    const float rf = (float)res - 1.f;
    const float posx = px * rf, posy = py * rf, posz = pz * rf;
    const float fx = floorf(posx), fy = floorf(posy), fz = floorf(posz);
    const float wx = posx - fx, wy = posy - fy, wz = posz - fz;
    const unsigned x0 = (unsigned)fx, y0 = (unsigned)fy, z0 = (unsigned)fz;
    const unsigned x1 = min(x0 + 1u, rm1), y1 = min(y0 + 1u, rm1), z1 = min(z0 + 1u, rm1);
    const float sx[2] = {1.f - wx, wx}, sy[2] = {1.f - wy, wy}, sz[2] = {1.f - wz, wz};
    unsigned tx[2], ty[2], tz[2];
    if (dense) { tx[0]=x0; tx[1]=x1; ty[0]=y0*res; ty[1]=y1*res; tz[0]=z0*res*res; tz[1]=z1*res*res; }
    else       { tx[0]=x0; tx[1]=x1; ty[0]=y0*P2;  ty[1]=y1*P2;  tz[0]=z0*P1;      tz[1]=z1*P1; }
    const unsigned short* tb = tb8 + ((size_t)lv << 19);
    float a0 = 0.f, a1 = 0.f;
    if (dense) {
        #pragma unroll
        for (int corner = 0; corner < 8; ++corner) {
            const int ox = (corner >> 2) & 1, oy = (corner >> 1) & 1, oz = corner & 1;
            const unsigned idx = (tx[ox] + ty[oy] + tz[oz]) & (TBLN - 1u);
            const unsigned short u = tb[idx];
            const float f0 = (float)(signed char)(u & 0xFF);
            const float f1 = (float)(signed char)(u >> 8);
            const float wc = sx[ox] * sy[oy] * sz[oz];
            a0 += wc * f0; a1 += wc * f1;
        }
    } else {
        #pragma unroll
        for (int corner = 0; corner < 8; ++corner) {
            const int ox = (corner >> 2) & 1, oy = (corner >> 1) & 1, oz = corner & 1;
            const unsigned idx = (tx[ox] ^ ty[oy] ^ tz[oz]) & (TBLN - 1u);
            const unsigned short u = tb[idx];
            const float f0 = (float)(signed char)(u & 0xFF);
            const float f1 = (float)(signed char)(u >> 8);
            const float wc = sx[ox] * sy[oy] * sz[oz];
            a0 += wc * f0; a1 += wc * f1;
        }
    }
    ra0 = a0; ra1 = a1;
}

// fp32 variant (fallback paths) — verified R4/R5 math
__device__ __forceinline__ void enc_f32(int lv, float px, float py, float pz,
                                        const GridParams& gp, const float* __restrict__ table,
                                        float& ra0, float& ra1)
{
    const unsigned res = gp.res[lv];
    const bool dense = (gp.dense_mask >> lv) & 1u;
    const unsigned rm1 = res - 1u;
    const float rf = (float)res - 1.f;
    const float posx = px * rf, posy = py * rf, posz = pz * rf;
    const float fx = floorf(posx), fy = floorf(posy), fz = floorf(posz);
    const float wx = posx - fx, wy = posy - fy, wz = posz - fz;
    const unsigned x0 = (unsigned)fx, y0 = (unsigned)fy, z0 = (unsigned)fz;
    const unsigned x1 = min(x0 + 1u, rm1), y1 = min(y0 + 1u, rm1), z1 = min(z0 + 1u, rm1);
    const float sx[2] = {1.f - wx, wx}, sy[2] = {1.f - wy, wy}, sz[2] = {1.f - wz, wz};
    unsigned tx[2], ty[2], tz[2];
    if (dense) { tx[0]=x0; tx[1]=x1; ty[0]=y0*res; ty[1]=y1*res; tz[0]=z0*res*res; tz[1]=z1*res*res; }
    else       { tx[0]=x0; tx[1]=x1; ty[0]=y0*P2;  ty[1]=y1*P2;  tz[0]=z0*P1;      tz[1]=z1*P1; }
    const float* tb = table + (((size_t)lv << 19) * 2u);
    float a0 = 0.f, a1 = 0.f;
    if (dense) {
        #pragma unroll
        for (int corner = 0; corner < 8; ++corner) {
            const int ox = (corner >> 2) & 1, oy = (corner >> 1) & 1, oz = corner & 1;
            const unsigned idx = (tx[ox] + ty[oy] + tz[oz]) & (TBLN - 1u);
            const float2 f2 = *reinterpret_cast<const float2*>(tb + (size_t)idx * 2u);
            const float wc = sx[ox] * sy[oy] * sz[oz];
            a0 += wc * f2.x; a1 += wc * f2.y;
        }
    } else {
        #pragma unroll
        for (int corner = 0; corner < 8; ++corner) {
            const int ox = (corner >> 2) & 1, oy = (corner >> 1) & 1, oz = corner & 1;
            const unsigned idx = (tx[ox] ^ ty[oy] ^ tz[oz]) & (TBLN - 1u);
            const float2 f2 = *reinterpret_cast<const float2*>(tb + (size_t)idx * 2u);
            const float wc = sx[ox] * sy[oy] * sz[oz];
            a0 += wc * f2.x; a1 += wc * f2.y;
        }
    }
    ra0 = a0; ra1 = a1;
}

// ---------------------------------------------------------------------------
// Gather: grid [8 pairs x C chunks], pair-major (per-pair int8 table = 1 MB
// -> L2-resident per XCD). planes: [pair][N] of 8B bf16 features.
// ---------------------------------------------------------------------------
__global__ __launch_bounds__(256, 5)
void gather_s8(const float* __restrict__ input, const unsigned short* __restrict__ tb8,
               const unsigned* __restrict__ scl, uint2v* __restrict__ planes,
               GridParams gp, int N)
{
    const int C = N >> 8;
    const int b = blockIdx.x;
    const int pair = b / C;
    const int chunk = b - pair * C;
    const int n = (chunk << 8) + threadIdx.x;

    float px, py, pz; load_pos(input, n, px, py, pz);

    const float d0 = __uint_as_float(scl[2 * pair    ]) * (1.f / 127.f);
    const float d1 = __uint_as_float(scl[2 * pair + 1]) * (1.f / 127.f);

    float a00, a01, a10, a11;
    enc_s8(2 * pair + 0, px, py, pz, gp, tb8, a00, a01);
    enc_s8(2 * pair + 1, px, py, pz, gp, tb8, a10, a11);

    uint2v q = { pkbf(a00 * d0, a01 * d0), pkbf(a10 * d1, a11 * d1) };
    planes[(size_t)pair * N + n] = q;
}

// fp32-table fallback gather
__global__ __launch_bounds__(256, 5)
void gather_f32(const float* __restrict__ input, const float* __restrict__ table,
                uint2v* __restrict__ planes, GridParams gp, int N)
{
    const int C = N >> 8;
    const int b = blockIdx.x;
    const int pair = b / C;
    const int chunk = b - pair * C;
    const int n = (chunk << 8) + threadIdx.x;

    float px, py, pz; load_pos(input, n, px, py, pz);
    float a00, a01, a10, a11;
    enc_f32(2 * pair + 0, px, py, pz, gp, table, a00, a01);
    enc_f32(2 * pair + 1, px, py, pz, gp, table, a10, a11);

    uint2v q = { pkbf(a00, a01), pkbf(a10, a11) };
    planes[(size_t)pair * N + n] = q;
}

// ---------------------------------------------------------------------------
// MLP kernel — exact R5 proven pipeline (no perm). Per-wave LDS 9216 B.
// ---------------------------------------------------------------------------
__global__ __launch_bounds__(256)
void nerf_mlp(const float* __restrict__ input, const uint2v* __restrict__ planes,
              const uint4v* __restrict__ wf, float* __restrict__ out, int N)
{
    __shared__ unsigned char smem[4 * 9216];
    const int tid  = threadIdx.x;
    const int lane = tid & 63;
    const int w    = tid >> 6;
    const int g    = lane >> 4, c = lane & 15;
    unsigned char* const sc = smem + w * 9216;

    const int n = blockIdx.x * 256 + tid;
    const int pbase = blockIdx.x * 256 + w * 64;

    const float2* ip = reinterpret_cast<const float2*>(input + (size_t)n * 6);
    const float2 iB = ip[1], iC = ip[2];

    unsigned shq[8], shl[8];
    {
        const float x = iB.y, y = iC.x, z = iC.y;
        const float x2 = x*x, y2 = y*y, z2 = z*z;
        const float xy = x*y, yz = y*z, xz = x*z;
        float s[16];
        s[0]  = 0.28209479177387814f;
        s[1]  = -0.48860251190291987f * y;
        s[2]  =  0.48860251190291987f * z;
        s[3]  = -0.48860251190291987f * x;
        s[4]  =  1.0925484305920792f * xy;
        s[5]  = -1.0925484305920792f * yz;
        s[6]  =  0.94617469575756f * z2 - 0.31539156525252005f;
        s[7]  = -1.0925484305920792f * xz;
        s[8]  =  0.5462742152960396f * (x2 - y2);
        s[9]  =  0.5900435899266435f * y * (-3.0f * x2 + y2);
        s[10] =  2.890611442640554f * xy * z;
        s[11] =  0.4570457994644657f * y * (1.0f - 5.0f * z2);
        s[12] =  0.3731763325901154f * z * (5.0f * z2 - 3.0f);
        s[13] =  0.4570457994644657f * x * (1.0f - 5.0f * z2);
        s[14] =  1.445305721320277f * z * (x2 - y2);
        s[15] =  0.5900435899266435f * x * (-x2 + 3.0f * y2);
        #pragma unroll
        for (int i = 0; i < 8; ++i) {
            unsigned h0 = f2bf(s[2*i]), h1 = f2bf(s[2*i+1]);
            shq[i] = h0 | (h1 << 16);
            shl[i] = pkbf(s[2*i] - bf2f(h0), s[2*i+1] - bf2f(h1));
        }
    }

    const f32x4 zz = {0.f, 0.f, 0.f, 0.f};

    short8 xb[4];
    #pragma unroll
    for (int pt = 0; pt < 4; ++pt) {
        const int p = pbase + pt * 16 + c;
        uint2v q0 = planes[(size_t)(2 * g)     * N + p];
        uint2v q1 = planes[(size_t)(2 * g + 1) * N + p];
        uint4v t = { q0.x, q0.y, q1.x, q1.y };
        xb[pt] = __builtin_bit_cast(short8, t);
    }

    f32x4 acc2[2][4];
    #pragma unroll
    for (int t = 0; t < 2; ++t)
        #pragma unroll
        for (int pt = 0; pt < 4; ++pt) acc2[t][pt] = zz;

    #pragma unroll
    for (int oc = 0; oc < 4; ++oc) {
        short8 a1_0 = __builtin_bit_cast(short8, wf[(2 * oc + 0) * 64 + lane]);
        short8 a1_1 = __builtin_bit_cast(short8, wf[(2 * oc + 1) * 64 + lane]);
        f32x4 d1[2][4];
        #pragma unroll
        for (int pt = 0; pt < 4; ++pt) {
            d1[0][pt] = MFMA(a1_0, xb[pt], zz);
            d1[1][pt] = MFMA(a1_1, xb[pt], zz);
        }
        #pragma unroll
        for (int t = 0; t < 2; ++t)
            #pragma unroll
            for (int pt = 0; pt < 4; ++pt) {
                const float e0 = fmaxf(d1[t][pt][0], 0.f), e1 = fmaxf(d1[t][pt][1], 0.f);
                const float e2 = fmaxf(d1[t][pt][2], 0.f), e3 = fmaxf(d1[t][pt][3], 0.f);
                uint2v q = { pkbf(e0, e1), pkbf(e2, e3) };
                *reinterpret_cast<uint2v*>(sc + (pt * 16 + c) * 80 + 32 * t + 8 * g) = q;
            }
        LGKM0();
        short8 a2_0 = __builtin_bit_cast(short8, wf[(8 + 0 * 4 + oc) * 64 + lane]);
        short8 a2_1 = __builtin_bit_cast(short8, wf[(8 + 1 * 4 + oc) * 64 + lane]);
        #pragma unroll
        for (int pt = 0; pt < 4; ++pt) {
            short8 b2 = *reinterpret_cast<const short8*>(sc + (pt * 16 + c) * 80 + g * 16);
            acc2[0][pt] = MFMA(a2_0, b2, acc2[0][pt]);
            acc2[1][pt] = MFMA(a2_1, b2, acc2[1][pt]);
        }
    }
    LGKM0();

    float sigv[4];
    #pragma unroll
    for (int pt = 0; pt < 4; ++pt) sigv[pt] = acc2[0][pt][0];

    const uint4v zq = { 0u, 0u, 0u, 0u };
    #pragma unroll
    for (int chunk = 0; chunk < 2; ++chunk) {
        if ((lane >> 5) == chunk) {
            unsigned char* rowh = sc + (lane & 31) * 144;
            unsigned char* rowl = rowh + 4608;
            uint4v h0 = { shq[0], shq[1], shq[2], shq[3] };
            uint4v h1 = { shq[4], shq[5], shq[6], shq[7] };
            uint4v l0 = { shl[0], shl[1], shl[2], shl[3] };
            uint4v l1 = { shl[4], shl[5], shl[6], shl[7] };
            *reinterpret_cast<uint4v*>(rowh +  0) = h0;
            *reinterpret_cast<uint4v*>(rowh + 16) = h1;
            *reinterpret_cast<uint4v*>(rowh + 96) = zq;
            *reinterpret_cast<uint4v*>(rowh +112) = zq;
            *reinterpret_cast<uint4v*>(rowl +  0) = l0;
            *reinterpret_cast<uint4v*>(rowl + 16) = l1;
            *reinterpret_cast<uint4v*>(rowl + 96) = zq;
            *reinterpret_cast<uint4v*>(rowl +112) = zq;
        }
        #pragma unroll
        for (int t = 0; t < 2; ++t)
            #pragma unroll
            for (int pl = 0; pl < 2; ++pl) {
                const int pt = chunk * 2 + pl;
                const float v0 = acc2[t][pt][0], v1 = acc2[t][pt][1];
                const float v2 = acc2[t][pt][2], v3 = acc2[t][pt][3];
                const unsigned h0 = f2bf(v0), h1 = f2bf(v1), h2 = f2bf(v2), h3 = f2bf(v3);
                uint2v qh = { h0 | (h1 << 16), h2 | (h3 << 16) };
                uint2v ql = { pkbf(v0 - bf2f(h0), v1 - bf2f(h1)),
                              pkbf(v2 - bf2f(h2), v3 - bf2f(h3)) };
                *reinterpret_cast<uint2v*>(sc + (pl * 16 + c) * 144 + 32 + 32 * t + 8 * g) = qh;
                *reinterpret_cast<uint2v*>(sc + 4608 + (pl * 16 + c) * 144 + 32 + 32 * t + 8 * g) = ql;
            }
        LGKM0();

        #pragma unroll
        for (int layer = 0; layer < 2; ++layer) {
            const int fb_hi = (layer == 0) ? 16 : 32;
            const int fb_lo = fb_hi + 8;
            short8 bh[2][2], bl[2][2];
            #pragma unroll
            for (int pl = 0; pl < 2; ++pl)
                #pragma unroll
                for (int ks = 0; ks < 2; ++ks) {
                    bh[pl][ks] = *reinterpret_cast<const short8*>(sc + (pl * 16 + c) * 144 + ks * 64 + g * 16);
                    bl[pl][ks] = *reinterpret_cast<const short8*>(sc + 4608 + (pl * 16 + c) * 144 + ks * 64 + g * 16);
                }
            LGKM0();
            #pragma unroll
            for (int ot = 0; ot < 4; ++ot) {
                short8 wh0 = __builtin_bit_cast(short8, wf[(fb_hi + ot * 2 + 0) * 64 + lane]);
                short8 wh1 = __builtin_bit_cast(short8, wf[(fb_hi + ot * 2 + 1) * 64 + lane]);
                short8 wl0 = __builtin_bit_cast(short8, wf[(fb_lo + ot * 2 + 0) * 64 + lane]);
                short8 wl1 = __builtin_bit_cast(short8, wf[(fb_lo + ot * 2 + 1) * 64 + lane]);
                #pragma unroll
                for (int pl = 0; pl < 2; ++pl) {
                    f32x4 d = MFMA(wh0, bh[pl][0], zz);
                    d = MFMA(wh1, bh[pl][1], d);
                    d = MFMA(wh0, bl[pl][0], d);
                    d = MFMA(wh1, bl[pl][1], d);
                    d = MFMA(wl0, bh[pl][0], d);
                    d = MFMA(wl1, bh[pl][1], d);
                    const float e0 = fmaxf(d[0], 0.f), e1 = fmaxf(d[1], 0.f);
                    const float e2 = fmaxf(d[2], 0.f), e3 = fmaxf(d[3], 0.f);
                    const unsigned h0 = f2bf(e0), h1 = f2bf(e1), h2 = f2bf(e2), h3 = f2bf(e3);
                    uint2v qh = { h0 | (h1 << 16), h2 | (h3 << 16) };
                    uint2v ql = { pkbf(e0 - bf2f(h0), e1 - bf2f(h1)),
                                  pkbf(e2 - bf2f(h2), e3 - bf2f(h3)) };
                    *reinterpret_cast<uint2v*>(sc + (pl * 16 + c) * 144 + 32 * ot + 8 * g) = qh;
                    *reinterpret_cast<uint2v*>(sc + 4608 + (pl * 16 + c) * 144 + 32 * ot + 8 * g) = ql;
                }
            }
            LGKM0();
        }

        {
            short8 bh[2][2], bl[2][2];
            #pragma unroll
            for (int pl = 0; pl < 2; ++pl)
                #pragma unroll
                for (int ks = 0; ks < 2; ++ks) {
                    bh[pl][ks] = *reinterpret_cast<const short8*>(sc + (pl * 16 + c) * 144 + ks * 64 + g * 16);
                    bl[pl][ks] = *reinterpret_cast<const short8*>(sc + 4608 + (pl * 16 + c) * 144 + ks * 64 + g * 16);
                }
            LGKM0();
            short8 ch0 = __builtin_bit_cast(short8, wf[(48 + 0) * 64 + lane]);
            short8 ch1 = __builtin_bit_cast(short8, wf[(48 + 1) * 64 + lane]);
            short8 cl0 = __builtin_bit_cast(short8, wf[(50 + 0) * 64 + lane]);
            short8 cl1 = __builtin_bit_cast(short8, wf[(50 + 1) * 64 + lane]);
            #pragma unroll
            for (int pl = 0; pl < 2; ++pl) {
                f32x4 d = MFMA(ch0, bh[pl][0], zz);
                d = MFMA(ch1, bh[pl][1], d);
                d = MFMA(ch0, bl[pl][0], d);
                d = MFMA(ch1, bl[pl][1], d);
                d = MFMA(cl0, bh[pl][0], d);
                d = MFMA(cl1, bh[pl][1], d);
                if (g == 0) {
                    const float r  = 1.f / (1.f + __expf(-d[0]));
                    const float gg = 1.f / (1.f + __expf(-d[1]));
                    const float bb = 1.f / (1.f + __expf(-d[2]));
                    const int pidx = blockIdx.x * 256 + w * 64 + chunk * 32 + pl * 16 + c;
                    float4 o4 = make_float4(r, gg, bb, sigv[chunk * 2 + pl]);
                    *reinterpret_cast<float4*>(out + (size_t)pidx * 4) = o4;
                }
            }
        }
    }
}

extern "C" void kernel_launch(void* const* d_in, const int* in_sizes, int n_in,
                              void* d_out, int out_size, void* d_ws, size_t ws_size,
                              hipStream_t stream) {
    (void)n_in; (void)out_size;
    const float* input = (const float*)d_in[0];
    const float* table = (const float*)d_in[1];
    const float* w1    = (const float*)d_in[2];
    const float* w2    = (const float*)d_in[3];
    const float* c1    = (const float*)d_in[4];
    const float* c2    = (const float*)d_in[5];
    const float* c3    = (const float*)d_in[6];
    float* out = (float*)d_out;
    const int N = in_sizes[0] / 6;

    GridParams gp;
    const double pls = exp2(log2(2048.0 * 16.0 / 16.0) / 15.0);
    unsigned dm = 0;
    for (int i = 0; i < LVLS; ++i) {
        const double r = ceil(16.0 * pow(pls, (double)i));
        const long long ri = (long long)r;
        gp.res[i] = (unsigned)ri;
        if (ri * ri * ri <= (long long)TBLN) dm |= (1u << i);
    }
    gp.dense_mask = dm;

    const size_t FRAGS_B  = 65536;                          // 52*64*16 used
    const size_t PLANES_B = (size_t)8 * (size_t)N * 8;      // 33.5 MB
    const size_t TB8_B    = (size_t)LVLS * TBLN * 2;        // 16.8 MB
    const size_t SCALES_B = 4096;                           // 16 used
    char* base = (char*)d_ws;
    uint4v* wf = (uint4v*)d_ws;
    const int C = N / 256;

    hipLaunchKernelGGL(prep_frags, dim3(52), dim3(64), 0, stream, w1, w2, c1, c2, c3, wf);

    const size_t need_s8 = FRAGS_B + PLANES_B + TB8_B + SCALES_B;   // ~50.4 MB
    if (ws_size >= need_s8) {
        uint2v*         planes = (uint2v*)(base + FRAGS_B);
        unsigned short* tb8    = (unsigned short*)(base + FRAGS_B + PLANES_B);
        unsigned*       scl    = (unsigned*)(base + FRAGS_B + PLANES_B + TB8_B);

        hipLaunchKernelGGL(zero16, dim3(1), dim3(16), 0, stream, scl);
        hipLaunchKernelGGL(absmax_lvl, dim3(LVLS * 32), dim3(256), 0, stream, table, scl);
        hipLaunchKernelGGL(quant_table, dim3(4096), dim3(256), 0, stream, table, scl, tb8);
        hipLaunchKernelGGL(gather_s8, dim3(8 * C), dim3(256), 0, stream,
                           input, (const unsigned short*)tb8, (const unsigned*)scl,
                           planes, gp, N);
        hipLaunchKernelGGL(nerf_mlp, dim3(C), dim3(256), 0, stream,
                           input, (const uint2v*)planes, (const uint4v*)wf, out, N);
    } else {
        // fp32-table fallback (needs only planes)
        uint2v* planes = (uint2v*)(base + FRAGS_B);
        hipLaunchKernelGGL(gather_f32, dim3(8 * C), dim3(256), 0, stream,
                           input, table, planes, gp, N);
        hipLaunchKernelGGL(nerf_mlp, dim3(C), dim3(256), 0, stream,
                           input, (const uint2v*)planes, (const uint4v*)wf, out, N);
    }
}

// Round 9
// 224.895 us; speedup vs baseline: 2.7610x; 1.2530x over previous
//
#include <hip/hip_runtime.h>
#include <cmath>

constexpr int LVLS = 16;
constexpr unsigned TBLN = 1u << 19;
constexpr unsigned P1 = 2654435761u;   // multiplies z
constexpr unsigned P2 = 805459861u;    // multiplies y

typedef __attribute__((ext_vector_type(8))) short short8;
typedef __attribute__((ext_vector_type(4))) float f32x4;
typedef __attribute__((ext_vector_type(4))) unsigned uint4v;
typedef __attribute__((ext_vector_type(2))) unsigned uint2v;

struct GridParams { unsigned res[LVLS]; unsigned dense_mask; };

__device__ __host__ __forceinline__ unsigned f2bf(float f) {
    union { float f; unsigned u; } v; v.f = f;
    unsigned u = v.u;
    u += 0x7fffu + ((u >> 16) & 1u);   // RNE
    return u >> 16;
}
__device__ __host__ __forceinline__ float bf2f(unsigned h) {
    union { unsigned u; float f; } v; v.u = h << 16; return v.f;
}
__device__ __forceinline__ unsigned pkbf(float lo, float hi) {
    return f2bf(lo) | (f2bf(hi) << 16);
}

#define LGKM0() do { asm volatile("s_waitcnt lgkmcnt(0)" ::: "memory"); \
                     __builtin_amdgcn_sched_barrier(0); } while (0)

#define MFMA(a,b,c) __builtin_amdgcn_mfma_f32_16x16x32_bf16((a),(b),(c),0,0,0)

__device__ __forceinline__ void load_pos(const float* __restrict__ input, int n,
                                         float& px, float& py, float& pz) {
    const float2* ip = reinterpret_cast<const float2*>(input + (size_t)n * 6);
    const float2 iA = ip[0], iB = ip[1];
    px = fminf(fmaxf((iA.x + 16.f) * (1.f / 32.f), 0.f), 1.f);
    py = fminf(fmaxf((iA.y + 16.f) * (1.f / 32.f), 0.f), 1.f);
    pz = fminf(fmaxf((iB.x + 16.f) * (1.f / 32.f), 0.f), 1.f);
}

// ---------------------------------------------------------------------------
// Prep: pack MLP weights into bf16 MFMA A-fragments (52 frags) — verified R4/R5
// ---------------------------------------------------------------------------
__global__ void prep_frags(const float* __restrict__ w1, const float* __restrict__ w2,
                           const float* __restrict__ c1, const float* __restrict__ c2,
                           const float* __restrict__ c3, uint4v* __restrict__ wf) {
    const int f = blockIdx.x;
    const int l = threadIdx.x;
    const int g = l >> 4, c = l & 15;
    float v[8];
    bool lo_part = false;
    if (f < 8) {
        int o = f * 16 + c;
        #pragma unroll
        for (int i = 0; i < 8; ++i) { int k = g * 8 + i; v[i] = w1[k * 128 + o]; }
    } else if (f < 16) {
        int idx = f - 8; int o = (idx >> 2) * 16 + c; int ks = idx & 3;
        #pragma unroll
        for (int i = 0; i < 8; ++i) {
            int k = ks * 32 + g * 8 + i;
            v[i] = (o < 31) ? w2[k * 31 + o] : 0.f;
        }
    } else if (f < 32) {
        int idx = (f - 16) & 7; lo_part = (f >= 24);
        int o = (idx >> 1) * 16 + c; int ks = idx & 1;
        #pragma unroll
        for (int i = 0; i < 8; ++i) {
            int k = ks * 32 + g * 8 + i;
            float x = 0.f;
            if (k < 16) x = c1[k * 64 + o];
            else if (k >= 17 && k <= 46) x = c1[(k - 1) * 64 + o];
            v[i] = x;
        }
    } else if (f < 48) {
        int idx = (f - 32) & 7; lo_part = (f >= 40);
        int o = (idx >> 1) * 16 + c; int ks = idx & 1;
        #pragma unroll
        for (int i = 0; i < 8; ++i) { int k = ks * 32 + g * 8 + i; v[i] = c2[k * 64 + o]; }
    } else {
        int idx = f - 48; lo_part = (idx >= 2); int ks = idx & 1;
        #pragma unroll
        for (int i = 0; i < 8; ++i) {
            int k = ks * 32 + g * 8 + i;
            v[i] = (c < 3) ? c3[k * 3 + c] : 0.f;
        }
    }
    if (lo_part) {
        #pragma unroll
        for (int i = 0; i < 8; ++i) v[i] = v[i] - bf2f(f2bf(v[i]));
    }
    uint4v q = { pkbf(v[0], v[1]), pkbf(v[2], v[3]), pkbf(v[4], v[5]), pkbf(v[6], v[7]) };
    wf[f * 64 + l] = q;
}

// ---------------------------------------------------------------------------
// int8 table pipeline: zero scales -> per-level absmax -> quantize
// ---------------------------------------------------------------------------
__global__ void zero16(unsigned* __restrict__ scl) {
    if (threadIdx.x < 16) scl[threadIdx.x] = 0u;
}

__global__ void absmax_lvl(const float* __restrict__ t, unsigned* __restrict__ scl) {
    __shared__ float red[256];
    const int tid = threadIdx.x;
    const int lv = blockIdx.x >> 5;
    const int ch = blockIdx.x & 31;
    const float4* p = reinterpret_cast<const float4*>(
        t + (size_t)lv * TBLN * 2u + (size_t)ch * 32768u);
    float m = 0.f;
    for (int i = tid; i < 8192; i += 256) {
        const float4 v = p[i];
        m = fmaxf(m, fmaxf(fmaxf(fabsf(v.x), fabsf(v.y)), fmaxf(fabsf(v.z), fabsf(v.w))));
    }
    red[tid] = m;
    __syncthreads();
    for (int s = 128; s > 0; s >>= 1) {
        if (tid < s) red[tid] = fmaxf(red[tid], red[tid + s]);
        __syncthreads();
    }
    if (tid == 0) atomicMax(&scl[lv], __float_as_uint(red[0]));
}

__global__ void quant_table(const float* __restrict__ t, const unsigned* __restrict__ scl,
                            unsigned short* __restrict__ o) {
    const int n = LVLS * (int)TBLN;
    int i = blockIdx.x * 256 + threadIdx.x;
    const int stride = gridDim.x * 256;
    for (; i < n; i += stride) {
        const int lv = i >> 19;
        const float scale = __uint_as_float(scl[lv]);
        const float inv = (scale > 0.f) ? (127.f / scale) : 0.f;
        const float2 v = reinterpret_cast<const float2*>(t)[i];
        const int q0 = (int)rintf(v.x * inv);
        const int q1 = (int)rintf(v.y * inv);
        o[i] = (unsigned short)((q0 & 0xFF) | ((q1 & 0xFF) << 8));
    }
}

// ---------------------------------------------------------------------------
// Merged-load helpers (reduce lane-addresses; values identical to scalar path)
// ---------------------------------------------------------------------------
__device__ __forceinline__ unsigned sel4(uint4v w, unsigned i) {  // i in [0,4)
    const unsigned lo = (i & 1u) ? w[1] : w[0];
    const unsigned hi = (i & 1u) ? w[3] : w[2];
    return (i & 2u) ? hi : lo;
}

// dense: entries i0 and i0+xd (xd in {0,1}); one aligned 16B load 87.5% of time
__device__ __forceinline__ void fetch_dense_pair(const unsigned short* __restrict__ tb,
                                                 unsigned i0, unsigned xd,
                                                 unsigned& e0, unsigned& e1) {
    const unsigned off = i0 & 7u;
    if (off + xd <= 7u) {
        const uint4v w = *reinterpret_cast<const uint4v*>(tb + (i0 & ~7u));
        const unsigned d0 = sel4(w, off >> 1);
        e0 = (off & 1u) ? (d0 >> 16) : (d0 & 0xFFFFu);
        const unsigned o1 = off + xd;
        const unsigned d1 = sel4(w, o1 >> 1);
        e1 = (o1 & 1u) ? (d1 >> 16) : (d1 & 0xFFFFu);
    } else {
        e0 = tb[i0];
        e1 = tb[i0 + xd];
    }
}

// hash: when x0 even and x1==x0+1, idx(x1)=idx(x0)^1 -> one aligned dword
__device__ __forceinline__ void fetch_hash_pair(const unsigned short* __restrict__ tb,
                                                unsigned x0, unsigned x1, unsigned h,
                                                unsigned& e0, unsigned& e1) {
    const unsigned i0 = (x0 ^ h) & (TBLN - 1u);
    if ((x1 == x0 + 1u) && ((x0 & 1u) == 0u)) {
        const unsigned pair = *reinterpret_cast<const unsigned*>(tb + (i0 & ~1u));
        const unsigned sw = i0 & 1u;
        e0 = sw ? (pair >> 16) : (pair & 0xFFFFu);
        e1 = sw ? (pair & 0xFFFFu) : (pair >> 16);
    } else {
        const unsigned i1 = (x1 ^ h) & (TBLN - 1u);
        e0 = tb[i0];
        e1 = tb[i1];
    }
}

// ---------------------------------------------------------------------------
// Trilinear hash-grid lookup — int8 table, merged x-pair loads.
// Raw integer accumulation; caller applies the per-level scale once.
// ---------------------------------------------------------------------------
__device__ __forceinline__ void enc_s8m(int lv, float px, float py, float pz,
                                        const GridParams& gp,
                                        const unsigned short* __restrict__ tb8,
                                        float& ra0, float& ra1)
{
    const unsigned res = gp.res[lv];
    const bool dense = (gp.dense_mask >> lv) & 1u;
    const unsigned rm1 = res - 1u;
    const float rf = (float)res - 1.f;
    const float posx = px * rf, posy = py * rf, posz = pz * rf;
    const float fx = floorf(posx), fy = floorf(posy), fz = floorf(posz);
    const float wx = posx - fx, wy = posy - fy, wz = posz - fz;
    const unsigned x0 = (unsigned)fx, y0 = (unsigned)fy, z0 = (unsigned)fz;
    const unsigned x1 = min(x0 + 1u, rm1), y1 = min(y0 + 1u, rm1), z1 = min(z0 + 1u, rm1);
    const unsigned xd = x1 - x0;
    const float sx0 = 1.f - wx, sx1 = wx;
    const float sy[2] = {1.f - wy, wy}, sz[2] = {1.f - wz, wz};
    unsigned hy[2], hz[2];
    if (dense) { hy[0] = y0 * res; hy[1] = y1 * res; hz[0] = z0 * res * res; hz[1] = z1 * res * res; }
    else       { hy[0] = y0 * P2;  hy[1] = y1 * P2;  hz[0] = z0 * P1;        hz[1] = z1 * P1; }
    const unsigned short* tb = tb8 + ((size_t)lv << 19);
    float a0 = 0.f, a1 = 0.f;
    if (dense) {
        // dense idx fits in res^3 <= TBLN: mask is a no-op, adjacency exact
        #pragma unroll
        for (int oy = 0; oy < 2; ++oy)
            #pragma unroll
            for (int oz = 0; oz < 2; ++oz) {
                unsigned e0, e1;
                const unsigned i0 = hy[oy] + hz[oz] + x0;
                fetch_dense_pair(tb, i0, xd, e0, e1);
                const float syz = sy[oy] * sz[oz];
                const float f00 = (float)(signed char)(e0 & 0xFFu), f01 = (float)(signed char)(e0 >> 8);
                const float f10 = (float)(signed char)(e1 & 0xFFu), f11 = (float)(signed char)(e1 >> 8);
                a0 += syz * (sx0 * f00 + sx1 * f10);
                a1 += syz * (sx0 * f01 + sx1 * f11);
            }
    } else {
        #pragma unroll
        for (int oy = 0; oy < 2; ++oy)
            #pragma unroll
            for (int oz = 0; oz < 2; ++oz) {
                unsigned e0, e1;
                fetch_hash_pair(tb, x0, x1, hy[oy] ^ hz[oz], e0, e1);
                const float syz = sy[oy] * sz[oz];
                const float f00 = (float)(signed char)(e0 & 0xFFu), f01 = (float)(signed char)(e0 >> 8);
                const float f10 = (float)(signed char)(e1 & 0xFFu), f11 = (float)(signed char)(e1 >> 8);
                a0 += syz * (sx0 * f00 + sx1 * f10);
                a1 += syz * (sx0 * f01 + sx1 * f11);
            }
    }
    ra0 = a0; ra1 = a1;
}

// fp32 variant (fallback path) — verified R4/R5 math
__device__ __forceinline__ void enc_f32(int lv, float px, float py, float pz,
                                        const GridParams& gp, const float* __restrict__ table,
                                        float& ra0, float& ra1)
{
    const unsigned res = gp.res[lv];
    const bool dense = (gp.dense_mask >> lv) & 1u;
    const unsigned rm1 = res - 1u;
    const float rf = (float)res - 1.f;
    const float posx = px * rf, posy = py * rf, posz = pz * rf;
    const float fx = floorf(posx), fy = floorf(posy), fz = floorf(posz);
    const float wx = posx - fx, wy = posy - fy, wz = posz - fz;
    const unsigned x0 = (unsigned)fx, y0 = (unsigned)fy, z0 = (unsigned)fz;
    const unsigned x1 = min(x0 + 1u, rm1), y1 = min(y0 + 1u, rm1), z1 = min(z0 + 1u, rm1);
    const float sx[2] = {1.f - wx, wx}, sy[2] = {1.f - wy, wy}, sz[2] = {1.f - wz, wz};
    unsigned tx[2], ty[2], tz[2];
    if (dense) { tx[0]=x0; tx[1]=x1; ty[0]=y0*res; ty[1]=y1*res; tz[0]=z0*res*res; tz[1]=z1*res*res; }
    else       { tx[0]=x0; tx[1]=x1; ty[0]=y0*P2;  ty[1]=y1*P2;  tz[0]=z0*P1;      tz[1]=z1*P1; }
    const float* tb = table + (((size_t)lv << 19) * 2u);
    float a0 = 0.f, a1 = 0.f;
    if (dense) {
        #pragma unroll
        for (int corner = 0; corner < 8; ++corner) {
            const int ox = (corner >> 2) & 1, oy = (corner >> 1) & 1, oz = corner & 1;
            const unsigned idx = (tx[ox] + ty[oy] + tz[oz]) & (TBLN - 1u);
            const float2 f2 = *reinterpret_cast<const float2*>(tb + (size_t)idx * 2u);
            const float wc = sx[ox] * sy[oy] * sz[oz];
            a0 += wc * f2.x; a1 += wc * f2.y;
        }
    } else {
        #pragma unroll
        for (int corner = 0; corner < 8; ++corner) {
            const int ox = (corner >> 2) & 1, oy = (corner >> 1) & 1, oz = corner & 1;
            const unsigned idx = (tx[ox] ^ ty[oy] ^ tz[oz]) & (TBLN - 1u);
            const float2 f2 = *reinterpret_cast<const float2*>(tb + (size_t)idx * 2u);
            const float wc = sx[ox] * sy[oy] * sz[oz];
            a0 += wc * f2.x; a1 += wc * f2.y;
        }
    }
    ra0 = a0; ra1 = a1;
}

// ---------------------------------------------------------------------------
// Gather: grid [8 pairs x C chunks], pair-major. planes: [pair][N] of 8B bf16.
// ---------------------------------------------------------------------------
__global__ __launch_bounds__(256, 5)
void gather_s8(const float* __restrict__ input, const unsigned short* __restrict__ tb8,
               const unsigned* __restrict__ scl, uint2v* __restrict__ planes,
               GridParams gp, int N)
{
    const int C = N >> 8;
    const int b = blockIdx.x;
    const int pair = b / C;
    const int chunk = b - pair * C;
    const int n = (chunk << 8) + threadIdx.x;

    float px, py, pz; load_pos(input, n, px, py, pz);

    const float d0 = __uint_as_float(scl[2 * pair    ]) * (1.f / 127.f);
    const float d1 = __uint_as_float(scl[2 * pair + 1]) * (1.f / 127.f);

    float a00, a01, a10, a11;
    enc_s8m(2 * pair + 0, px, py, pz, gp, tb8, a00, a01);
    enc_s8m(2 * pair + 1, px, py, pz, gp, tb8, a10, a11);

    uint2v q = { pkbf(a00 * d0, a01 * d0), pkbf(a10 * d1, a11 * d1) };
    planes[(size_t)pair * N + n] = q;
}

// fp32-table fallback gather
__global__ __launch_bounds__(256, 5)
void gather_f32(const float* __restrict__ input, const float* __restrict__ table,
                uint2v* __restrict__ planes, GridParams gp, int N)
{
    const int C = N >> 8;
    const int b = blockIdx.x;
    const int pair = b / C;
    const int chunk = b - pair * C;
    const int n = (chunk << 8) + threadIdx.x;

    float px, py, pz; load_pos(input, n, px, py, pz);
    float a00, a01, a10, a11;
    enc_f32(2 * pair + 0, px, py, pz, gp, table, a00, a01);
    enc_f32(2 * pair + 1, px, py, pz, gp, table, a10, a11);

    uint2v q = { pkbf(a00, a01), pkbf(a10, a11) };
    planes[(size_t)pair * N + n] = q;
}

// ---------------------------------------------------------------------------
// MLP kernel — exact R5/R8 proven pipeline. Per-wave LDS 9216 B.
// ---------------------------------------------------------------------------
__global__ __launch_bounds__(256)
void nerf_mlp(const float* __restrict__ input, const uint2v* __restrict__ planes,
              const uint4v* __restrict__ wf, float* __restrict__ out, int N)
{
    __shared__ unsigned char smem[4 * 9216];
    const int tid  = threadIdx.x;
    const int lane = tid & 63;
    const int w    = tid >> 6;
    const int g    = lane >> 4, c = lane & 15;
    unsigned char* const sc = smem + w * 9216;

    const int n = blockIdx.x * 256 + tid;
    const int pbase = blockIdx.x * 256 + w * 64;

    const float2* ip = reinterpret_cast<const float2*>(input + (size_t)n * 6);
    const float2 iB = ip[1], iC = ip[2];

    unsigned shq[8], shl[8];
    {
        const float x = iB.y, y = iC.x, z = iC.y;
        const float x2 = x*x, y2 = y*y, z2 = z*z;
        const float xy = x*y, yz = y*z, xz = x*z;
        float s[16];
        s[0]  = 0.28209479177387814f;
        s[1]  = -0.48860251190291987f * y;
        s[2]  =  0.48860251190291987f * z;
        s[3]  = -0.48860251190291987f * x;
        s[4]  =  1.0925484305920792f * xy;
        s[5]  = -1.0925484305920792f * yz;
        s[6]  =  0.94617469575756f * z2 - 0.31539156525252005f;
        s[7]  = -1.0925484305920792f * xz;
        s[8]  =  0.5462742152960396f * (x2 - y2);
        s[9]  =  0.5900435899266435f * y * (-3.0f * x2 + y2);
        s[10] =  2.890611442640554f * xy * z;
        s[11] =  0.4570457994644657f * y * (1.0f - 5.0f * z2);
        s[12] =  0.3731763325901154f * z * (5.0f * z2 - 3.0f);
        s[13] =  0.4570457994644657f * x * (1.0f - 5.0f * z2);
        s[14] =  1.445305721320277f * z * (x2 - y2);
        s[15] =  0.5900435899266435f * x * (-x2 + 3.0f * y2);
        #pragma unroll
        for (int i = 0; i < 8; ++i) {
            unsigned h0 = f2bf(s[2*i]), h1 = f2bf(s[2*i+1]);
            shq[i] = h0 | (h1 << 16);
            shl[i] = pkbf(s[2*i] - bf2f(h0), s[2*i+1] - bf2f(h1));
        }
    }

    const f32x4 zz = {0.f, 0.f, 0.f, 0.f};

    short8 xb[4];
    #pragma unroll
    for (int pt = 0; pt < 4; ++pt) {
        const int p = pbase + pt * 16 + c;
        uint2v q0 = planes[(size_t)(2 * g)     * N + p];
        uint2v q1 = planes[(size_t)(2 * g + 1) * N + p];
        uint4v t = { q0.x, q0.y, q1.x, q1.y };
        xb[pt] = __builtin_bit_cast(short8, t);
    }

    f32x4 acc2[2][4];
    #pragma unroll
    for (int t = 0; t < 2; ++t)
        #pragma unroll
        for (int pt = 0; pt < 4; ++pt) acc2[t][pt] = zz;

    #pragma unroll
    for (int oc = 0; oc < 4; ++oc) {
        short8 a1_0 = __builtin_bit_cast(short8, wf[(2 * oc + 0) * 64 + lane]);
        short8 a1_1 = __builtin_bit_cast(short8, wf[(2 * oc + 1) * 64 + lane]);
        f32x4 d1[2][4];
        #pragma unroll
        for (int pt = 0; pt < 4; ++pt) {
            d1[0][pt] = MFMA(a1_0, xb[pt], zz);
            d1[1][pt] = MFMA(a1_1, xb[pt], zz);
        }
        #pragma unroll
        for (int t = 0; t < 2; ++t)
            #pragma unroll
            for (int pt = 0; pt < 4; ++pt) {
                const float e0 = fmaxf(d1[t][pt][0], 0.f), e1 = fmaxf(d1[t][pt][1], 0.f);
                const float e2 = fmaxf(d1[t][pt][2], 0.f), e3 = fmaxf(d1[t][pt][3], 0.f);
                uint2v q = { pkbf(e0, e1), pkbf(e2, e3) };
                *reinterpret_cast<uint2v*>(sc + (pt * 16 + c) * 80 + 32 * t + 8 * g) = q;
            }
        LGKM0();
        short8 a2_0 = __builtin_bit_cast(short8, wf[(8 + 0 * 4 + oc) * 64 + lane]);
        short8 a2_1 = __builtin_bit_cast(short8, wf[(8 + 1 * 4 + oc) * 64 + lane]);
        #pragma unroll
        for (int pt = 0; pt < 4; ++pt) {
            short8 b2 = *reinterpret_cast<const short8*>(sc + (pt * 16 + c) * 80 + g * 16);
            acc2[0][pt] = MFMA(a2_0, b2, acc2[0][pt]);
            acc2[1][pt] = MFMA(a2_1, b2, acc2[1][pt]);
        }
    }
    LGKM0();

    float sigv[4];
    #pragma unroll
    for (int pt = 0; pt < 4; ++pt) sigv[pt] = acc2[0][pt][0];

    const uint4v zq = { 0u, 0u, 0u, 0u };
    #pragma unroll
    for (int chunk = 0; chunk < 2; ++chunk) {
        if ((lane >> 5) == chunk) {
            unsigned char* rowh = sc + (lane & 31) * 144;
            unsigned char* rowl = rowh + 4608;
            uint4v h0 = { shq[0], shq[1], shq[2], shq[3] };
            uint4v h1 = { shq[4], shq[5], shq[6], shq[7] };
            uint4v l0 = { shl[0], shl[1], shl[2], shl[3] };
            uint4v l1 = { shl[4], shl[5], shl[6], shl[7] };
            *reinterpret_cast<uint4v*>(rowh +  0) = h0;
            *reinterpret_cast<uint4v*>(rowh + 16) = h1;
            *reinterpret_cast<uint4v*>(rowh + 96) = zq;
            *reinterpret_cast<uint4v*>(rowh +112) = zq;
            *reinterpret_cast<uint4v*>(rowl +  0) = l0;
            *reinterpret_cast<uint4v*>(rowl + 16) = l1;
            *reinterpret_cast<uint4v*>(rowl + 96) = zq;
            *reinterpret_cast<uint4v*>(rowl +112) = zq;
        }
        #pragma unroll
        for (int t = 0; t < 2; ++t)
            #pragma unroll
            for (int pl = 0; pl < 2; ++pl) {
                const int pt = chunk * 2 + pl;
                const float v0 = acc2[t][pt][0], v1 = acc2[t][pt][1];
                const float v2 = acc2[t][pt][2], v3 = acc2[t][pt][3];
                const unsigned h0 = f2bf(v0), h1 = f2bf(v1), h2 = f2bf(v2), h3 = f2bf(v3);
                uint2v qh = { h0 | (h1 << 16), h2 | (h3 << 16) };
                uint2v ql = { pkbf(v0 - bf2f(h0), v1 - bf2f(h1)),
                              pkbf(v2 - bf2f(h2), v3 - bf2f(h3)) };
                *reinterpret_cast<uint2v*>(sc + (pl * 16 + c) * 144 + 32 + 32 * t + 8 * g) = qh;
                *reinterpret_cast<uint2v*>(sc + 4608 + (pl * 16 + c) * 144 + 32 + 32 * t + 8 * g) = ql;
            }
        LGKM0();

        #pragma unroll
        for (int layer = 0; layer < 2; ++layer) {
            const int fb_hi = (layer == 0) ? 16 : 32;
            const int fb_lo = fb_hi + 8;
            short8 bh[2][2], bl[2][2];
            #pragma unroll
            for (int pl = 0; pl < 2; ++pl)
                #pragma unroll
                for (int ks = 0; ks < 2; ++ks) {
                    bh[pl][ks] = *reinterpret_cast<const short8*>(sc + (pl * 16 + c) * 144 + ks * 64 + g * 16);
                    bl[pl][ks] = *reinterpret_cast<const short8*>(sc + 4608 + (pl * 16 + c) * 144 + ks * 64 + g * 16);
                }
            LGKM0();
            #pragma unroll
            for (int ot = 0; ot < 4; ++ot) {
                short8 wh0 = __builtin_bit_cast(short8, wf[(fb_hi + ot * 2 + 0) * 64 + lane]);
                short8 wh1 = __builtin_bit_cast(short8, wf[(fb_hi + ot * 2 + 1) * 64 + lane]);
                short8 wl0 = __builtin_bit_cast(short8, wf[(fb_lo + ot * 2 + 0) * 64 + lane]);
                short8 wl1 = __builtin_bit_cast(short8, wf[(fb_lo + ot * 2 + 1) * 64 + lane]);
                #pragma unroll
                for (int pl = 0; pl < 2; ++pl) {
                    f32x4 d = MFMA(wh0, bh[pl][0], zz);
                    d = MFMA(wh1, bh[pl][1], d);
                    d = MFMA(wh0, bl[pl][0], d);
                    d = MFMA(wh1, bl[pl][1], d);
                    d = MFMA(wl0, bh[pl][0], d);
                    d = MFMA(wl1, bh[pl][1], d);
                    const float e0 = fmaxf(d[0], 0.f), e1 = fmaxf(d[1], 0.f);
                    const float e2 = fmaxf(d[2], 0.f), e3 = fmaxf(d[3], 0.f);
                    const unsigned h0 = f2bf(e0), h1 = f2bf(e1), h2 = f2bf(e2), h3 = f2bf(e3);
                    uint2v qh = { h0 | (h1 << 16), h2 | (h3 << 16) };
                    uint2v ql = { pkbf(e0 - bf2f(h0), e1 - bf2f(h1)),
                                  pkbf(e2 - bf2f(h2), e3 - bf2f(h3)) };
                    *reinterpret_cast<uint2v*>(sc + (pl * 16 + c) * 144 + 32 * ot + 8 * g) = qh;
                    *reinterpret_cast<uint2v*>(sc + 4608 + (pl * 16 + c) * 144 + 32 * ot + 8 * g) = ql;
                }
            }
            LGKM0();
        }

        {
            short8 bh[2][2], bl[2][2];
            #pragma unroll
            for (int pl = 0; pl < 2; ++pl)
                #pragma unroll
                for (int ks = 0; ks < 2; ++ks) {
                    bh[pl][ks] = *reinterpret_cast<const short8*>(sc + (pl * 16 + c) * 144 + ks * 64 + g * 16);
                    bl[pl][ks] = *reinterpret_cast<const short8*>(sc + 4608 + (pl * 16 + c) * 144 + ks * 64 + g * 16);
                }
            LGKM0();
            short8 ch0 = __builtin_bit_cast(short8, wf[(48 + 0) * 64 + lane]);
            short8 ch1 = __builtin_bit_cast(short8, wf[(48 + 1) * 64 + lane]);
            short8 cl0 = __builtin_bit_cast(short8, wf[(50 + 0) * 64 + lane]);
            short8 cl1 = __builtin_bit_cast(short8, wf[(50 + 1) * 64 + lane]);
            #pragma unroll
            for (int pl = 0; pl < 2; ++pl) {
                f32x4 d = MFMA(ch0, bh[pl][0], zz);
                d = MFMA(ch1, bh[pl][1], d);
                d = MFMA(ch0, bl[pl][0], d);
                d = MFMA(ch1, bl[pl][1], d);
                d = MFMA(cl0, bh[pl][0], d);
                d = MFMA(cl1, bh[pl][1], d);
                if (g == 0) {
                    const float r  = 1.f / (1.f + __expf(-d[0]));
                    const float gg = 1.f / (1.f + __expf(-d[1]));
                    const float bb = 1.f / (1.f + __expf(-d[2]));
                    const int pidx = blockIdx.x * 256 + w * 64 + chunk * 32 + pl * 16 + c;
                    float4 o4 = make_float4(r, gg, bb, sigv[chunk * 2 + pl]);
                    *reinterpret_cast<float4*>(out + (size_t)pidx * 4) = o4;
                }
            }
        }
    }
}

extern "C" void kernel_launch(void* const* d_in, const int* in_sizes, int n_in,
                              void* d_out, int out_size, void* d_ws, size_t ws_size,
                              hipStream_t stream) {
    (void)n_in; (void)out_size;
    const float* input = (const float*)d_in[0];
    const float* table = (const float*)d_in[1];
    const float* w1    = (const float*)d_in[2];
    const float* w2    = (const float*)d_in[3];
    const float* c1    = (const float*)d_in[4];
    const float* c2    = (const float*)d_in[5];
    const float* c3    = (const float*)d_in[6];
    float* out = (float*)d_out;
    const int N = in_sizes[0] / 6;

    GridParams gp;
    const double pls = exp2(log2(2048.0 * 16.0 / 16.0) / 15.0);
    unsigned dm = 0;
    for (int i = 0; i < LVLS; ++i) {
        const double r = ceil(16.0 * pow(pls, (double)i));
        const long long ri = (long long)r;
        gp.res[i] = (unsigned)ri;
        if (ri * ri * ri <= (long long)TBLN) dm |= (1u << i);
    }
    gp.dense_mask = dm;

    const size_t FRAGS_B  = 65536;
    const size_t PLANES_B = (size_t)8 * (size_t)N * 8;
    const size_t TB8_B    = (size_t)LVLS * TBLN * 2;
    const size_t SCALES_B = 4096;
    char* base = (char*)d_ws;
    uint4v* wf = (uint4v*)d_ws;
    const int C = N / 256;

    hipLaunchKernelGGL(prep_frags, dim3(52), dim3(64), 0, stream, w1, w2, c1, c2, c3, wf);

    const size_t need_s8 = FRAGS_B + PLANES_B + TB8_B + SCALES_B;
    if (ws_size >= need_s8) {
        uint2v*         planes = (uint2v*)(base + FRAGS_B);
        unsigned short* tb8    = (unsigned short*)(base + FRAGS_B + PLANES_B);
        unsigned*       scl    = (unsigned*)(base + FRAGS_B + PLANES_B + TB8_B);

        hipLaunchKernelGGL(zero16, dim3(1), dim3(16), 0, stream, scl);
        hipLaunchKernelGGL(absmax_lvl, dim3(LVLS * 32), dim3(256), 0, stream, table, scl);
        hipLaunchKernelGGL(quant_table, dim3(4096), dim3(256), 0, stream, table, scl, tb8);
        hipLaunchKernelGGL(gather_s8, dim3(8 * C), dim3(256), 0, stream,
                           input, (const unsigned short*)tb8, (const unsigned*)scl,
                           planes, gp, N);
        hipLaunchKernelGGL(nerf_mlp, dim3(C), dim3(256), 0, stream,
                           input, (const uint2v*)planes, (const uint4v*)wf, out, N);
    } else {
        uint2v* planes = (uint2v*)(base + FRAGS_B);
        hipLaunchKernelGGL(gather_f32, dim3(8 * C), dim3(256), 0, stream,
                           input, table, planes, gp, N);
        hipLaunchKernelGGL(nerf_mlp, dim3(C), dim3(256), 0, stream,
                           input, (const uint2v*)planes, (const uint4v*)wf, out, N);
    }
}

// Round 13
// 224.002 us; speedup vs baseline: 2.7720x; 1.0040x over previous
//
#include <hip/hip_runtime.h>
#include <cmath>

constexpr int LVLS = 16;
constexpr unsigned TBLN = 1u << 19;
constexpr unsigned P1 = 2654435761u;   // multiplies z
constexpr unsigned P2 = 805459861u;    // multiplies y

typedef __attribute__((ext_vector_type(8))) short short8;
typedef __attribute__((ext_vector_type(4))) float f32x4;
typedef __attribute__((ext_vector_type(4))) unsigned uint4v;
typedef __attribute__((ext_vector_type(2))) unsigned uint2v;

struct GridParams { unsigned res[LVLS]; unsigned dense_mask; };

__device__ __host__ __forceinline__ unsigned f2bf(float f) {
    union { float f; unsigned u; } v; v.f = f;
    unsigned u = v.u;
    u += 0x7fffu + ((u >> 16) & 1u);   // RNE
    return u >> 16;
}
__device__ __host__ __forceinline__ float bf2f(unsigned h) {
    union { unsigned u; float f; } v; v.u = h << 16; return v.f;
}
__device__ __forceinline__ unsigned pkbf(float lo, float hi) {
    return f2bf(lo) | (f2bf(hi) << 16);
}

#define LGKM0() do { asm volatile("s_waitcnt lgkmcnt(0)" ::: "memory"); \
                     __builtin_amdgcn_sched_barrier(0); } while (0)

#define MFMA(a,b,c) __builtin_amdgcn_mfma_f32_16x16x32_bf16((a),(b),(c),0,0,0)

__device__ __forceinline__ void load_pos(const float* __restrict__ input, int n,
                                         float& px, float& py, float& pz) {
    const float2* ip = reinterpret_cast<const float2*>(input + (size_t)n * 6);
    const float2 iA = ip[0], iB = ip[1];
    px = fminf(fmaxf((iA.x + 16.f) * (1.f / 32.f), 0.f), 1.f);
    py = fminf(fmaxf((iA.y + 16.f) * (1.f / 32.f), 0.f), 1.f);
    pz = fminf(fmaxf((iB.x + 16.f) * (1.f / 32.f), 0.f), 1.f);
}

// ---------------------------------------------------------------------------
// Prep: pack MLP weights into bf16 MFMA A-fragments (52 frags) — verified R4/R5.
// Block f==0 additionally zeroes the 16 scale slots (replaces zero16 kernel).
// ---------------------------------------------------------------------------
__global__ void prep_frags(const float* __restrict__ w1, const float* __restrict__ w2,
                           const float* __restrict__ c1, const float* __restrict__ c2,
                           const float* __restrict__ c3, uint4v* __restrict__ wf,
                           unsigned* __restrict__ scl) {
    const int f = blockIdx.x;
    const int l = threadIdx.x;
    if (f == 0 && l < 16) scl[l] = 0u;
    const int g = l >> 4, c = l & 15;
    float v[8];
    bool lo_part = false;
    if (f < 8) {
        int o = f * 16 + c;
        #pragma unroll
        for (int i = 0; i < 8; ++i) { int k = g * 8 + i; v[i] = w1[k * 128 + o]; }
    } else if (f < 16) {
        int idx = f - 8; int o = (idx >> 2) * 16 + c; int ks = idx & 3;
        #pragma unroll
        for (int i = 0; i < 8; ++i) {
            int k = ks * 32 + g * 8 + i;
            v[i] = (o < 31) ? w2[k * 31 + o] : 0.f;
        }
    } else if (f < 32) {
        int idx = (f - 16) & 7; lo_part = (f >= 24);
        int o = (idx >> 1) * 16 + c; int ks = idx & 1;
        #pragma unroll
        for (int i = 0; i < 8; ++i) {
            int k = ks * 32 + g * 8 + i;
            float x = 0.f;
            if (k < 16) x = c1[k * 64 + o];
            else if (k >= 17 && k <= 46) x = c1[(k - 1) * 64 + o];
            v[i] = x;
        }
    } else if (f < 48) {
        int idx = (f - 32) & 7; lo_part = (f >= 40);
        int o = (idx >> 1) * 16 + c; int ks = idx & 1;
        #pragma unroll
        for (int i = 0; i < 8; ++i) { int k = ks * 32 + g * 8 + i; v[i] = c2[k * 64 + o]; }
    } else {
        int idx = f - 48; lo_part = (idx >= 2); int ks = idx & 1;
        #pragma unroll
        for (int i = 0; i < 8; ++i) {
            int k = ks * 32 + g * 8 + i;
            v[i] = (c < 3) ? c3[k * 3 + c] : 0.f;
        }
    }
    if (lo_part) {
        #pragma unroll
        for (int i = 0; i < 8; ++i) v[i] = v[i] - bf2f(f2bf(v[i]));
    }
    uint4v q = { pkbf(v[0], v[1]), pkbf(v[2], v[3]), pkbf(v[4], v[5]), pkbf(v[6], v[7]) };
    wf[f * 64 + l] = q;
}

// ---------------------------------------------------------------------------
// int8 table pipeline: per-level absmax -> quantize
// ---------------------------------------------------------------------------
__global__ void absmax_lvl(const float* __restrict__ t, unsigned* __restrict__ scl) {
    __shared__ float red[256];
    const int tid = threadIdx.x;
    const int lv = blockIdx.x >> 5;
    const int ch = blockIdx.x & 31;
    const float4* p = reinterpret_cast<const float4*>(
        t + (size_t)lv * TBLN * 2u + (size_t)ch * 32768u);
    float m = 0.f;
    for (int i = tid; i < 8192; i += 256) {
        const float4 v = p[i];
        m = fmaxf(m, fmaxf(fmaxf(fabsf(v.x), fabsf(v.y)), fmaxf(fabsf(v.z), fabsf(v.w))));
    }
    red[tid] = m;
    __syncthreads();
    for (int s = 128; s > 0; s >>= 1) {
        if (tid < s) red[tid] = fmaxf(red[tid], red[tid + s]);
        __syncthreads();
    }
    if (tid == 0) atomicMax(&scl[lv], __float_as_uint(red[0]));
}

__global__ void quant_table(const float* __restrict__ t, const unsigned* __restrict__ scl,
                            unsigned short* __restrict__ o) {
    const int n = LVLS * (int)TBLN;
    int i = blockIdx.x * 256 + threadIdx.x;
    const int stride = gridDim.x * 256;
    for (; i < n; i += stride) {
        const int lv = i >> 19;
        const float scale = __uint_as_float(scl[lv]);
        const float inv = (scale > 0.f) ? (127.f / scale) : 0.f;
        const float2 v = reinterpret_cast<const float2*>(t)[i];
        const int q0 = (int)rintf(v.x * inv);
        const int q1 = (int)rintf(v.y * inv);
        o[i] = (unsigned short)((q0 & 0xFF) | ((q1 & 0xFF) << 8));
    }
}

// ---------------------------------------------------------------------------
// Merged-load helpers (verified R9)
// ---------------------------------------------------------------------------
__device__ __forceinline__ unsigned sel4(uint4v w, unsigned i) {
    const unsigned lo = (i & 1u) ? w[1] : w[0];
    const unsigned hi = (i & 1u) ? w[3] : w[2];
    return (i & 2u) ? hi : lo;
}

__device__ __forceinline__ void fetch_dense_pair(const unsigned short* __restrict__ tb,
                                                 unsigned i0, unsigned xd,
                                                 unsigned& e0, unsigned& e1) {
    const unsigned off = i0 & 7u;
    if (off + xd <= 7u) {
        const uint4v w = *reinterpret_cast<const uint4v*>(tb + (i0 & ~7u));
        const unsigned d0 = sel4(w, off >> 1);
        e0 = (off & 1u) ? (d0 >> 16) : (d0 & 0xFFFFu);
        const unsigned o1 = off + xd;
        const unsigned d1 = sel4(w, o1 >> 1);
        e1 = (o1 & 1u) ? (d1 >> 16) : (d1 & 0xFFFFu);
    } else {
        e0 = tb[i0];
        e1 = tb[i0 + xd];
    }
}

__device__ __forceinline__ void fetch_hash_pair(const unsigned short* __restrict__ tb,
                                                unsigned x0, unsigned x1, unsigned h,
                                                unsigned& e0, unsigned& e1) {
    const unsigned i0 = (x0 ^ h) & (TBLN - 1u);
    if ((x1 == x0 + 1u) && ((x0 & 1u) == 0u)) {
        const unsigned pair = *reinterpret_cast<const unsigned*>(tb + (i0 & ~1u));
        const unsigned sw = i0 & 1u;
        e0 = sw ? (pair >> 16) : (pair & 0xFFFFu);
        e1 = sw ? (pair & 0xFFFFu) : (pair >> 16);
    } else {
        const unsigned i1 = (x1 ^ h) & (TBLN - 1u);
        e0 = tb[i0];
        e1 = tb[i1];
    }
}

// ---------------------------------------------------------------------------
// Trilinear int8 lookup — merged x-pair loads, dense_mask-aware (verified R9)
// ---------------------------------------------------------------------------
__device__ __forceinline__ void enc_s8m(int lv, float px, float py, float pz,
                                        const GridParams& gp,
                                        const unsigned short* __restrict__ tb8,
                                        float& ra0, float& ra1)
{
    const unsigned res = gp.res[lv];
    const bool dense = (gp.dense_mask >> lv) & 1u;
    const unsigned rm1 = res - 1u;
    const float rf = (float)res - 1.f;
    const float posx = px * rf, posy = py * rf, posz = pz * rf;
    const float fx = floorf(posx), fy = floorf(posy), fz = floorf(posz);
    const float wx = posx - fx, wy = posy - fy, wz = posz - fz;
    const unsigned x0 = (unsigned)fx, y0 = (unsigned)fy, z0 = (unsigned)fz;
    const unsigned x1 = min(x0 + 1u, rm1), y1 = min(y0 + 1u, rm1), z1 = min(z0 + 1u, rm1);
    const unsigned xd = x1 - x0;
    const float sx0 = 1.f - wx, sx1 = wx;
    const float sy[2] = {1.f - wy, wy}, sz[2] = {1.f - wz, wz};
    unsigned hy[2], hz[2];
    if (dense) { hy[0] = y0 * res; hy[1] = y1 * res; hz[0] = z0 * res * res; hz[1] = z1 * res * res; }
    else       { hy[0] = y0 * P2;  hy[1] = y1 * P2;  hz[0] = z0 * P1;        hz[1] = z1 * P1; }
    const unsigned short* tb = tb8 + ((size_t)lv << 19);
    float a0 = 0.f, a1 = 0.f;
    if (dense) {
        #pragma unroll
        for (int oy = 0; oy < 2; ++oy)
            #pragma unroll
            for (int oz = 0; oz < 2; ++oz) {
                unsigned e0, e1;
                const unsigned i0 = hy[oy] + hz[oz] + x0;
                fetch_dense_pair(tb, i0, xd, e0, e1);
                const float syz = sy[oy] * sz[oz];
                const float f00 = (float)(signed char)(e0 & 0xFFu), f01 = (float)(signed char)(e0 >> 8);
                const float f10 = (float)(signed char)(e1 & 0xFFu), f11 = (float)(signed char)(e1 >> 8);
                a0 += syz * (sx0 * f00 + sx1 * f10);
                a1 += syz * (sx0 * f01 + sx1 * f11);
            }
    } else {
        #pragma unroll
        for (int oy = 0; oy < 2; ++oy)
            #pragma unroll
            for (int oz = 0; oz < 2; ++oz) {
                unsigned e0, e1;
                fetch_hash_pair(tb, x0, x1, hy[oy] ^ hz[oz], e0, e1);
                const float syz = sy[oy] * sz[oz];
                const float f00 = (float)(signed char)(e0 & 0xFFu), f01 = (float)(signed char)(e0 >> 8);
                const float f10 = (float)(signed char)(e1 & 0xFFu), f11 = (float)(signed char)(e1 >> 8);
                a0 += syz * (sx0 * f00 + sx1 * f10);
                a1 += syz * (sx0 * f01 + sx1 * f11);
            }
    }
    ra0 = a0; ra1 = a1;
}

// fp32 variant (fallback path) — verified R4/R5 math
__device__ __forceinline__ void enc_f32(int lv, float px, float py, float pz,
                                        const GridParams& gp, const float* __restrict__ table,
                                        float& ra0, float& ra1)
{
    const unsigned res = gp.res[lv];
    const bool dense = (gp.dense_mask >> lv) & 1u;
    const unsigned rm1 = res - 1u;
    const float rf = (float)res - 1.f;
    const float posx = px * rf, posy = py * rf, posz = pz * rf;
    const float fx = floorf(posx), fy = floorf(posy), fz = floorf(posz);
    const float wx = posx - fx, wy = posy - fy, wz = posz - fz;
    const unsigned x0 = (unsigned)fx, y0 = (unsigned)fy, z0 = (unsigned)fz;
    const unsigned x1 = min(x0 + 1u, rm1), y1 = min(y0 + 1u, rm1), z1 = min(z0 + 1u, rm1);
    const float sx[2] = {1.f - wx, wx}, sy[2] = {1.f - wy, wy}, sz[2] = {1.f - wz, wz};
    unsigned tx[2], ty[2], tz[2];
    if (dense) { tx[0]=x0; tx[1]=x1; ty[0]=y0*res; ty[1]=y1*res; tz[0]=z0*res*res; tz[1]=z1*res*res; }
    else       { tx[0]=x0; tx[1]=x1; ty[0]=y0*P2;  ty[1]=y1*P2;  tz[0]=z0*P1;      tz[1]=z1*P1; }
    const float* tb = table + (((size_t)lv << 19) * 2u);
    float a0 = 0.f, a1 = 0.f;
    if (dense) {
        #pragma unroll
        for (int corner = 0; corner < 8; ++corner) {
            const int ox = (corner >> 2) & 1, oy = (corner >> 1) & 1, oz = corner & 1;
            const unsigned idx = (tx[ox] + ty[oy] + tz[oz]) & (TBLN - 1u);
            const float2 f2 = *reinterpret_cast<const float2*>(tb + (size_t)idx * 2u);
            const float wc = sx[ox] * sy[oy] * sz[oz];
            a0 += wc * f2.x; a1 += wc * f2.y;
        }
    } else {
        #pragma unroll
        for (int corner = 0; corner < 8; ++corner) {
            const int ox = (corner >> 2) & 1, oy = (corner >> 1) & 1, oz = corner & 1;
            const unsigned idx = (tx[ox] ^ ty[oy] ^ tz[oz]) & (TBLN - 1u);
            const float2 f2 = *reinterpret_cast<const float2*>(tb + (size_t)idx * 2u);
            const float wc = sx[ox] * sy[oy] * sz[oz];
            a0 += wc * f2.x; a1 += wc * f2.y;
        }
    }
    ra0 = a0; ra1 = a1;
}

// ---------------------------------------------------------------------------
// Gather: grid [8 pairs x C chunks], pair-major. planes: [pair][N] of 8B bf16.
// Nontemporal planes stores (stream-once; keep L2 for the tables).
// ---------------------------------------------------------------------------
__global__ __launch_bounds__(256, 5)
void gather_s8(const float* __restrict__ input, const unsigned short* __restrict__ tb8,
               const unsigned* __restrict__ scl, uint2v* __restrict__ planes,
               GridParams gp, int N)
{
    const int C = N >> 8;
    const int b = blockIdx.x;
    const int pair = b / C;
    const int chunk = b - pair * C;
    const int n = (chunk << 8) + threadIdx.x;

    float px, py, pz; load_pos(input, n, px, py, pz);

    const float d0 = __uint_as_float(scl[2 * pair    ]) * (1.f / 127.f);
    const float d1 = __uint_as_float(scl[2 * pair + 1]) * (1.f / 127.f);

    float a00, a01, a10, a11;
    enc_s8m(2 * pair + 0, px, py, pz, gp, tb8, a00, a01);
    enc_s8m(2 * pair + 1, px, py, pz, gp, tb8, a10, a11);

    uint2v q = { pkbf(a00 * d0, a01 * d0), pkbf(a10 * d1, a11 * d1) };
    __builtin_nontemporal_store(q, &planes[(size_t)pair * N + n]);
}

// fp32-table fallback gather
__global__ __launch_bounds__(256, 5)
void gather_f32(const float* __restrict__ input, const float* __restrict__ table,
                uint2v* __restrict__ planes, GridParams gp, int N)
{
    const int C = N >> 8;
    const int b = blockIdx.x;
    const int pair = b / C;
    const int chunk = b - pair * C;
    const int n = (chunk << 8) + threadIdx.x;

    float px, py, pz; load_pos(input, n, px, py, pz);
    float a00, a01, a10, a11;
    enc_f32(2 * pair + 0, px, py, pz, gp, table, a00, a01);
    enc_f32(2 * pair + 1, px, py, pz, gp, table, a10, a11);

    uint2v q = { pkbf(a00, a01), pkbf(a10, a11) };
    planes[(size_t)pair * N + n] = q;
}

// ---------------------------------------------------------------------------
// MLP kernel — exact R5/R9 proven pipeline. Per-wave LDS 9216 B.
// Nontemporal planes loads (stream-once).
// ---------------------------------------------------------------------------
__global__ __launch_bounds__(256)
void nerf_mlp(const float* __restrict__ input, const uint2v* __restrict__ planes,
              const uint4v* __restrict__ wf, float* __restrict__ out, int N)
{
    __shared__ unsigned char smem[4 * 9216];
    const int tid  = threadIdx.x;
    const int lane = tid & 63;
    const int w    = tid >> 6;
    const int g    = lane >> 4, c = lane & 15;
    unsigned char* const sc = smem + w * 9216;

    const int n = blockIdx.x * 256 + tid;
    const int pbase = blockIdx.x * 256 + w * 64;

    const float2* ip = reinterpret_cast<const float2*>(input + (size_t)n * 6);
    const float2 iB = ip[1], iC = ip[2];

    unsigned shq[8], shl[8];
    {
        const float x = iB.y, y = iC.x, z = iC.y;
        const float x2 = x*x, y2 = y*y, z2 = z*z;
        const float xy = x*y, yz = y*z, xz = x*z;
        float s[16];
        s[0]  = 0.28209479177387814f;
        s[1]  = -0.48860251190291987f * y;
        s[2]  =  0.48860251190291987f * z;
        s[3]  = -0.48860251190291987f * x;
        s[4]  =  1.0925484305920792f * xy;
        s[5]  = -1.0925484305920792f * yz;
        s[6]  =  0.94617469575756f * z2 - 0.31539156525252005f;
        s[7]  = -1.0925484305920792f * xz;
        s[8]  =  0.5462742152960396f * (x2 - y2);
        s[9]  =  0.5900435899266435f * y * (-3.0f * x2 + y2);
        s[10] =  2.890611442640554f * xy * z;
        s[11] =  0.4570457994644657f * y * (1.0f - 5.0f * z2);
        s[12] =  0.3731763325901154f * z * (5.0f * z2 - 3.0f);
        s[13] =  0.4570457994644657f * x * (1.0f - 5.0f * z2);
        s[14] =  1.445305721320277f * z * (x2 - y2);
        s[15] =  0.5900435899266435f * x * (-x2 + 3.0f * y2);
        #pragma unroll
        for (int i = 0; i < 8; ++i) {
            unsigned h0 = f2bf(s[2*i]), h1 = f2bf(s[2*i+1]);
            shq[i] = h0 | (h1 << 16);
            shl[i] = pkbf(s[2*i] - bf2f(h0), s[2*i+1] - bf2f(h1));
        }
    }

    const f32x4 zz = {0.f, 0.f, 0.f, 0.f};

    short8 xb[4];
    #pragma unroll
    for (int pt = 0; pt < 4; ++pt) {
        const int p = pbase + pt * 16 + c;
        uint2v q0 = __builtin_nontemporal_load(&planes[(size_t)(2 * g)     * N + p]);
        uint2v q1 = __builtin_nontemporal_load(&planes[(size_t)(2 * g + 1) * N + p]);
        uint4v t = { q0.x, q0.y, q1.x, q1.y };
        xb[pt] = __builtin_bit_cast(short8, t);
    }

    f32x4 acc2[2][4];
    #pragma unroll
    for (int t = 0; t < 2; ++t)
        #pragma unroll
        for (int pt = 0; pt < 4; ++pt) acc2[t][pt] = zz;

    #pragma unroll
    for (int oc = 0; oc < 4; ++oc) {
        short8 a1_0 = __builtin_bit_cast(short8, wf[(2 * oc + 0) * 64 + lane]);
        short8 a1_1 = __builtin_bit_cast(short8, wf[(2 * oc + 1) * 64 + lane]);
        f32x4 d1[2][4];
        #pragma unroll
        for (int pt = 0; pt < 4; ++pt) {
            d1[0][pt] = MFMA(a1_0, xb[pt], zz);
            d1[1][pt] = MFMA(a1_1, xb[pt], zz);
        }
        #pragma unroll
        for (int t = 0; t < 2; ++t)
            #pragma unroll
            for (int pt = 0; pt < 4; ++pt) {
                const float e0 = fmaxf(d1[t][pt][0], 0.f), e1 = fmaxf(d1[t][pt][1], 0.f);
                const float e2 = fmaxf(d1[t][pt][2], 0.f), e3 = fmaxf(d1[t][pt][3], 0.f);
                uint2v q = { pkbf(e0, e1), pkbf(e2, e3) };
                *reinterpret_cast<uint2v*>(sc + (pt * 16 + c) * 80 + 32 * t + 8 * g) = q;
            }
        LGKM0();
        short8 a2_0 = __builtin_bit_cast(short8, wf[(8 + 0 * 4 + oc) * 64 + lane]);
        short8 a2_1 = __builtin_bit_cast(short8, wf[(8 + 1 * 4 + oc) * 64 + lane]);
        #pragma unroll
        for (int pt = 0; pt < 4; ++pt) {
            short8 b2 = *reinterpret_cast<const short8*>(sc + (pt * 16 + c) * 80 + g * 16);
            acc2[0][pt] = MFMA(a2_0, b2, acc2[0][pt]);
            acc2[1][pt] = MFMA(a2_1, b2, acc2[1][pt]);
        }
    }
    LGKM0();

    float sigv[4];
    #pragma unroll
    for (int pt = 0; pt < 4; ++pt) sigv[pt] = acc2[0][pt][0];

    const uint4v zq = { 0u, 0u, 0u, 0u };
    #pragma unroll
    for (int chunk = 0; chunk < 2; ++chunk) {
        if ((lane >> 5) == chunk) {
            unsigned char* rowh = sc + (lane & 31) * 144;
            unsigned char* rowl = rowh + 4608;
            uint4v h0 = { shq[0], shq[1], shq[2], shq[3] };
            uint4v h1 = { shq[4], shq[5], shq[6], shq[7] };
            uint4v l0 = { shl[0], shl[1], shl[2], shl[3] };
            uint4v l1 = { shl[4], shl[5], shl[6], shl[7] };
            *reinterpret_cast<uint4v*>(rowh +  0) = h0;
            *reinterpret_cast<uint4v*>(rowh + 16) = h1;
            *reinterpret_cast<uint4v*>(rowh + 96) = zq;
            *reinterpret_cast<uint4v*>(rowh +112) = zq;
            *reinterpret_cast<uint4v*>(rowl +  0) = l0;
            *reinterpret_cast<uint4v*>(rowl + 16) = l1;
            *reinterpret_cast<uint4v*>(rowl + 96) = zq;
            *reinterpret_cast<uint4v*>(rowl +112) = zq;
        }
        #pragma unroll
        for (int t = 0; t < 2; ++t)
            #pragma unroll
            for (int pl = 0; pl < 2; ++pl) {
                const int pt = chunk * 2 + pl;
                const float v0 = acc2[t][pt][0], v1 = acc2[t][pt][1];
                const float v2 = acc2[t][pt][2], v3 = acc2[t][pt][3];
                const unsigned h0 = f2bf(v0), h1 = f2bf(v1), h2 = f2bf(v2), h3 = f2bf(v3);
                uint2v qh = { h0 | (h1 << 16), h2 | (h3 << 16) };
                uint2v ql = { pkbf(v0 - bf2f(h0), v1 - bf2f(h1)),
                              pkbf(v2 - bf2f(h2), v3 - bf2f(h3)) };
                *reinterpret_cast<uint2v*>(sc + (pl * 16 + c) * 144 + 32 + 32 * t + 8 * g) = qh;
                *reinterpret_cast<uint2v*>(sc + 4608 + (pl * 16 + c) * 144 + 32 + 32 * t + 8 * g) = ql;
            }
        LGKM0();

        #pragma unroll
        for (int layer = 0; layer < 2; ++layer) {
            const int fb_hi = (layer == 0) ? 16 : 32;
            const int fb_lo = fb_hi + 8;
            short8 bh[2][2], bl[2][2];
            #pragma unroll
            for (int pl = 0; pl < 2; ++pl)
                #pragma unroll
                for (int ks = 0; ks < 2; ++ks) {
                    bh[pl][ks] = *reinterpret_cast<const short8*>(sc + (pl * 16 + c) * 144 + ks * 64 + g * 16);
                    bl[pl][ks] = *reinterpret_cast<const short8*>(sc + 4608 + (pl * 16 + c) * 144 + ks * 64 + g * 16);
                }
            LGKM0();
            #pragma unroll
            for (int ot = 0; ot < 4; ++ot) {
                short8 wh0 = __builtin_bit_cast(short8, wf[(fb_hi + ot * 2 + 0) * 64 + lane]);
                short8 wh1 = __builtin_bit_cast(short8, wf[(fb_hi + ot * 2 + 1) * 64 + lane]);
                short8 wl0 = __builtin_bit_cast(short8, wf[(fb_lo + ot * 2 + 0) * 64 + lane]);
                short8 wl1 = __builtin_bit_cast(short8, wf[(fb_lo + ot * 2 + 1) * 64 + lane]);
                #pragma unroll
                for (int pl = 0; pl < 2; ++pl) {
                    f32x4 d = MFMA(wh0, bh[pl][0], zz);
                    d = MFMA(wh1, bh[pl][1], d);
                    d = MFMA(wh0, bl[pl][0], d);
                    d = MFMA(wh1, bl[pl][1], d);
                    d = MFMA(wl0, bh[pl][0], d);
                    d = MFMA(wl1, bh[pl][1], d);
                    const float e0 = fmaxf(d[0], 0.f), e1 = fmaxf(d[1], 0.f);
                    const float e2 = fmaxf(d[2], 0.f), e3 = fmaxf(d[3], 0.f);
                    const unsigned h0 = f2bf(e0), h1 = f2bf(e1), h2 = f2bf(e2), h3 = f2bf(e3);
                    uint2v qh = { h0 | (h1 << 16), h2 | (h3 << 16) };
                    uint2v ql = { pkbf(e0 - bf2f(h0), e1 - bf2f(h1)),
                                  pkbf(e2 - bf2f(h2), e3 - bf2f(h3)) };
                    *reinterpret_cast<uint2v*>(sc + (pl * 16 + c) * 144 + 32 * ot + 8 * g) = qh;
                    *reinterpret_cast<uint2v*>(sc + 4608 + (pl * 16 + c) * 144 + 32 * ot + 8 * g) = ql;
                }
            }
            LGKM0();
        }

        {
            short8 bh[2][2], bl[2][2];
            #pragma unroll
            for (int pl = 0; pl < 2; ++pl)
                #pragma unroll
                for (int ks = 0; ks < 2; ++ks) {
                    bh[pl][ks] = *reinterpret_cast<const short8*>(sc + (pl * 16 + c) * 144 + ks * 64 + g * 16);
                    bl[pl][ks] = *reinterpret_cast<const short8*>(sc + 4608 + (pl * 16 + c) * 144 + ks * 64 + g * 16);
                }
            LGKM0();
            short8 ch0 = __builtin_bit_cast(short8, wf[(48 + 0) * 64 + lane]);
            short8 ch1 = __builtin_bit_cast(short8, wf[(48 + 1) * 64 + lane]);
            short8 cl0 = __builtin_bit_cast(short8, wf[(50 + 0) * 64 + lane]);
            short8 cl1 = __builtin_bit_cast(short8, wf[(50 + 1) * 64 + lane]);
            #pragma unroll
            for (int pl = 0; pl < 2; ++pl) {
                f32x4 d = MFMA(ch0, bh[pl][0], zz);
                d = MFMA(ch1, bh[pl][1], d);
                d = MFMA(ch0, bl[pl][0], d);
                d = MFMA(ch1, bl[pl][1], d);
                d = MFMA(cl0, bh[pl][0], d);
                d = MFMA(cl1, bh[pl][1], d);
                if (g == 0) {
                    const float r  = 1.f / (1.f + __expf(-d[0]));
                    const float gg = 1.f / (1.f + __expf(-d[1]));
                    const float bb = 1.f / (1.f + __expf(-d[2]));
                    const int pidx = blockIdx.x * 256 + w * 64 + chunk * 32 + pl * 16 + c;
                    float4 o4 = make_float4(r, gg, bb, sigv[chunk * 2 + pl]);
                    *reinterpret_cast<float4*>(out + (size_t)pidx * 4) = o4;
                }
            }
        }
    }
}

extern "C" void kernel_launch(void* const* d_in, const int* in_sizes, int n_in,
                              void* d_out, int out_size, void* d_ws, size_t ws_size,
                              hipStream_t stream) {
    (void)n_in; (void)out_size;
    const float* input = (const float*)d_in[0];
    const float* table = (const float*)d_in[1];
    const float* w1    = (const float*)d_in[2];
    const float* w2    = (const float*)d_in[3];
    const float* c1    = (const float*)d_in[4];
    const float* c2    = (const float*)d_in[5];
    const float* c3    = (const float*)d_in[6];
    float* out = (float*)d_out;
    const int N = in_sizes[0] / 6;

    GridParams gp;
    const double pls = exp2(log2(2048.0 * 16.0 / 16.0) / 15.0);
    unsigned dm = 0;
    for (int i = 0; i < LVLS; ++i) {
        const double r = ceil(16.0 * pow(pls, (double)i));
        const long long ri = (long long)r;
        gp.res[i] = (unsigned)ri;
        if (ri * ri * ri <= (long long)TBLN) dm |= (1u << i);
    }
    gp.dense_mask = dm;

    const size_t FRAGS_B  = 65536;
    const size_t PLANES_B = (size_t)8 * (size_t)N * 8;   // 33.5 MB
    const size_t TB8_B    = (size_t)LVLS * TBLN * 2;     // 16.8 MB
    const size_t SCALES_B = 4096;
    char* base = (char*)d_ws;
    uint4v* wf = (uint4v*)d_ws;
    const int C = N / 256;

    const size_t need_s8 = FRAGS_B + PLANES_B + TB8_B + SCALES_B;
    if (ws_size >= need_s8) {
        uint2v*         planes = (uint2v*)(base + FRAGS_B);
        unsigned short* tb8    = (unsigned short*)(base + FRAGS_B + PLANES_B);
        unsigned*       scl    = (unsigned*)(base + FRAGS_B + PLANES_B + TB8_B);

        hipLaunchKernelGGL(prep_frags, dim3(52), dim3(64), 0, stream,
                           w1, w2, c1, c2, c3, wf, scl);
        hipLaunchKernelGGL(absmax_lvl, dim3(LVLS * 32), dim3(256), 0, stream, table, scl);
        hipLaunchKernelGGL(quant_table, dim3(4096), dim3(256), 0, stream, table, scl, tb8);
        hipLaunchKernelGGL(gather_s8, dim3(8 * C), dim3(256), 0, stream,
                           input, (const unsigned short*)tb8, (const unsigned*)scl,
                           planes, gp, N);
        hipLaunchKernelGGL(nerf_mlp, dim3(C), dim3(256), 0, stream,
                           input, (const uint2v*)planes, (const uint4v*)wf, out, N);
    } else {
        uint2v* planes = (uint2v*)(base + FRAGS_B);
        unsigned* scl  = (unsigned*)(base + FRAGS_B);  // unused by fallback gather
        hipLaunchKernelGGL(prep_frags, dim3(52), dim3(64), 0, stream,
                           w1, w2, c1, c2, c3, wf, scl);
        hipLaunchKernelGGL(gather_f32, dim3(8 * C), dim3(256), 0, stream,
                           input, table, planes, gp, N);
        hipLaunchKernelGGL(nerf_mlp, dim3(C), dim3(256), 0, stream,
                           input, (const uint2v*)planes, (const uint4v*)wf, out, N);
    }
}